// Round 6
// baseline (1244.915 us; speedup 1.0000x reference)
//
#include <hip/hip_runtime.h>
#include <hip/hip_bf16.h>
#include <hip/hip_fp16.h>

typedef __hip_bfloat16 bf16;
typedef __attribute__((ext_vector_type(8))) short short8;
typedef __attribute__((ext_vector_type(4))) float float4v;

#define T_  5
#define H_  64
#define W_  96
#define HW_ (H_*W_)
#define C_  256
#define NH_ 8
#define DH_ 32
#define NL_ 5
#define NP_ 4
#define LQ_ (T_*HW_)
#define UNITS_ (LQ_*NH_)          // 245760

// padded geometry: [T][66][98][256] bf16
#define PH_ 66
#define PW_ 98

static __device__ __forceinline__ void gl2lds16(const bf16* g, bf16* l){
  __builtin_amdgcn_global_load_lds(
      (const __attribute__((address_space(1))) unsigned int*)g,
      (__attribute__((address_space(3))) unsigned int*)l, 16, 0, 0);
}

// ------------------------------------------------------- bilinear (zero pad)
static __device__ __forceinline__ float bilin2(const float* __restrict__ img,
                                               float px, float py){
  float x0f = floorf(px), y0f = floorf(py);
  int x0 = (int)x0f, y0 = (int)y0f;
  float fx = px - x0f, fy = py - y0f;
  int x1 = x0+1, y1 = y0+1;
  bool vx0 = (x0>=0)&&(x0<W_), vx1 = (x1>=0)&&(x1<W_);
  bool vy0 = (y0>=0)&&(y0<H_), vy1 = (y1>=0)&&(y1<H_);
  float c00 = (vx0&&vy0)? img[y0*W_+x0] : 0.f;
  float c10 = (vx1&&vy0)? img[y0*W_+x1] : 0.f;
  float c01 = (vx0&&vy1)? img[y1*W_+x0] : 0.f;
  float c11 = (vx1&&vy1)? img[y1*W_+x1] : 0.f;
  return c00*(1.f-fx)*(1.f-fy) + c10*fx*(1.f-fy) + c01*(1.f-fx)*fy + c11*fx*fy;
}

// ------------------------------------------------------------- mega prologue
#define MG_PAD   960
#define MG_WT    1025
#define MG_INIT  336
#define MG_FA    120
#define MG_BZ    405
__global__ __launch_bounds__(256) void mega0_k(
    const float* __restrict__ in0, const float* __restrict__ in1,
    bf16* __restrict__ pad0, bf16* __restrict__ pad1,
    const float* __restrict__ wv, const float* __restrict__ wo,
    const float* __restrict__ wa, const float* __restrict__ wout,
    const float* __restrict__ bo, const float* __restrict__ ba,
    bf16* __restrict__ WTv, bf16* __restrict__ WToa, bf16* __restrict__ WTout,
    float* __restrict__ boa, unsigned* __restrict__ ctr,
    const float* __restrict__ ff, const float* __restrict__ fb,
    float* __restrict__ flows)
{
  __shared__ __align__(16) char smem[33792];
  int b = blockIdx.x, tid = threadIdx.x;
  if (b < MG_PAD){
    bf16 (*sb)[66] = (bf16(*)[66])smem;
    int z = b / 480, r = b - z*480;
    int t = r / 96, bxp = r - t*96;
    const float* in = z ? in1 : in0;
    bf16* pad       = z ? pad1 : pad0;
    int pix0 = bxp*64;
    int pl = tid & 63, cg = tid >> 6;
    #pragma unroll 4
    for (int it=0; it<64; ++it){
      int c = it*4 + cg;
      sb[c][pl] = __float2bfloat16(in[((size_t)t*C_ + c)*HW_ + pix0 + pl]);
    }
    __syncthreads();
    for (int p=0; p<64; ++p){
      int pix = pix0 + p;
      int y = pix/W_, x = pix - y*W_;
      pad[(((size_t)t*PH_ + y+1)*PW_ + x+1)*C_ + tid] = sb[tid][p];
    }
    return;
  }
  b -= MG_PAD;
  if (b < MG_WT){
    if (b == 1024){
      #pragma unroll
      for (int k=0;k<2;++k){
        int n = tid + k*256;
        float v = 0.f;
        if (n < 320) v = bo[n]; else if (n < 480) v = ba[n-320];
        boa[n] = v;
      }
      if (tid < 16) ctr[tid] = 0u;     // alignment-barrier counters
      return;
    }
    float* ld = (float*)smem;
    const float* src; bf16* dst;
    if (b < 256){ src = wv + (size_t)b*2304; dst = WTv + (size_t)b*2304; }
    else if (b < 768){
      int n = b-256; dst = WToa + (size_t)n*2304;
      src = (n<320) ? (wo + (size_t)n*2304)
          : ((n<480) ? (wa + (size_t)(n-320)*2304) : (const float*)0);
    } else { int n = b-768; src = wout + (size_t)n*2304; dst = WTout + (size_t)n*2304; }
    if (src){
      #pragma unroll
      for (int k=0;k<9;++k) ld[tid + k*256] = src[tid + k*256];
      __syncthreads();
      #pragma unroll
      for (int k=0;k<9;++k){
        int o = tid + k*256; int tap = o >> 8, ci = o & 255;
        dst[o] = __float2bfloat16(ld[ci*9 + tap]);
      }
    } else {
      #pragma unroll
      for (int k=0;k<9;++k) dst[tid + k*256] = __float2bfloat16(0.f);
    }
    return;
  }
  b -= MG_WT;
  if (b < MG_INIT){
    int i = b*256 + tid;            // < 86016
    const int per = 2*HW_;
    int f = i/per, r = i - f*per;
    if (f < 4) flows[f*per + r]          = ff[i];
    else       flows[(10+(f-4))*per + r] = fb[(f-4)*per + r];
    return;
  }
  b -= MG_INIT;
  if (b < MG_FA){
    int ci = b / 24;
    int pix = (b - ci*24)*256 + tid;
    const int dsts[5] = {4,7,9,13,14};
    const float* A; const float* S;
    switch(ci){
      case 0: A = ff;          S = ff + 2*HW_; break;
      case 1: A = ff + 2*HW_;  S = ff + 4*HW_; break;
      case 2: A = ff + 4*HW_;  S = ff + 6*HW_; break;
      case 3: A = fb + 2*HW_;  S = fb;         break;
      default:A = fb + 4*HW_;  S = fb + 2*HW_; break;
    }
    float* D = flows + dsts[ci]*2*HW_;
    float ax = A[pix], ay = A[HW_+pix];
    float px = (float)(pix % W_) + ax;
    float py = (float)(pix / W_) + ay;
    D[pix]      = ax + bilin2(S,      px, py);
    D[HW_+pix]  = ay + bilin2(S+HW_,  px, py);
    return;
  }
  b -= MG_FA;
  {
    int idx = b*256 + tid;          // < 103680 exactly
    int pair = idx / 10368, r = idx - pair*10368;
    int pxi = r >> 5, q8 = r & 31;
    int t = pair >> 1, z = pair & 1;
    int y, x;
    if (pxi < 98){ y = 0;  x = pxi; }
    else if (pxi < 196){ y = 65; x = pxi-98; }
    else if (pxi < 260){ y = pxi-196+1; x = 0; }
    else { y = pxi-260+1; x = 97; }
    bf16* pad = z ? pad1 : pad0;
    uint4 zz; zz.x = zz.y = zz.z = zz.w = 0u;
    *(uint4*)(pad + (((size_t)t*PH_ + y)*PW_ + x)*C_ + q8*8) = zz;
  }
}

// ------------------------------------------------- flow compose stages B + C
__global__ __launch_bounds__(256) void flowBC_k(const float* __restrict__ ff,
                                                const float* __restrict__ fb,
                                                float* __restrict__ flows){
  int gy = blockIdx.y;
  int pix = blockIdx.x*256 + threadIdx.x;
  float gx = (float)(pix % W_), gyy = (float)(pix / W_);
  if (gy == 0){
    const float* A   = flows + 4*2*HW_;
    const float* S23 = ff + 4*HW_;
    const float* S34 = ff + 6*HW_;
    float ax = A[pix], ay = A[HW_+pix];
    float px = gx + ax, py = gyy + ay;
    float c3x = ax + bilin2(S23,      px, py);
    float c3y = ay + bilin2(S23+HW_,  px, py);
    float* D3 = flows + 5*2*HW_;
    D3[pix] = c3x; D3[HW_+pix] = c3y;
    px = gx + c3x; py = gyy + c3y;
    float* D4 = flows + 6*2*HW_;
    D4[pix]     = c3x + bilin2(S34,     px, py);
    D4[HW_+pix] = c3y + bilin2(S34+HW_, px, py);
  } else if (gy == 1){
    const float* A = flows + 7*2*HW_;
    const float* S = ff + 6*HW_;
    float ax = A[pix], ay = A[HW_+pix];
    float px = gx + ax, py = gyy + ay;
    float* D = flows + 8*2*HW_;
    D[pix]     = ax + bilin2(S,     px, py);
    D[HW_+pix] = ay + bilin2(S+HW_, px, py);
  } else {
    const float* A = flows + 14*2*HW_;
    const float* S = fb;
    float ax = A[pix], ay = A[HW_+pix];
    float px = gx + ax, py = gyy + ay;
    float* D = flows + 15*2*HW_;
    D[pix]     = ax + bilin2(S,     px, py);
    D[HW_+pix] = ay + bilin2(S+HW_, px, py);
  }
}

// ----------------------------------------------------------- implicit GEMM
// R0-verified structure: BM=128, BN=256, BK=64, 4 waves, wave tile 64x128,
// 48 KB LDS -> 2 blocks/CU. Frozen (pipelining attempts R1/R4 were neutral).
#define BM 128
#define BN 256
#define BK 64

// fused val (byy 0, N=256) + oa (byy 1..2, N=512) conv-GEMM
__global__ __launch_bounds__(256,2) void gemm12_k(const bf16* __restrict__ Av,
                                                  const bf16* __restrict__ Aq,
                                                  const bf16* __restrict__ WTv,
                                                  const bf16* __restrict__ WToa,
                                                  const float* __restrict__ bv,
                                                  const float* __restrict__ boa,
                                                  bf16* __restrict__ outv,
                                                  float* __restrict__ P,
                                                  float* __restrict__ aw){
  __shared__ __align__(16) bf16 As[BM*BK];   // 16 KB
  __shared__ __align__(16) bf16 Bs[BN*BK];   // 32 KB
  int tid = threadIdx.x;
  int lane = tid & 63, wvi = tid >> 6;
  int wm = wvi & 1, wn = wvi >> 1;
  int quad = lane >> 4, l15 = lane & 15;
  int bx = blockIdx.x, byy = blockIdx.y;
  bool isval = byy == 0;
  const bf16* Apad  = isval ? Av  : Aq;
  const bf16* WT    = isval ? WTv : WToa;
  const float* bias = isval ? bv  : boa;
  int nby = isval ? 0 : byy - 1;

  int srow = tid >> 3;
  int c8   = (tid & 7) ^ (srow & 7);
  long abase[4];
  #pragma unroll
  for (int j=0;j<4;++j){
    int p = j*32 + srow;
    int Pm = bx*BM + p;
    int t = Pm / HW_, rem = Pm - t*HW_;
    int y = rem / W_, x = rem - y*W_;
    abase[j] = ((long)(t*PH_ + y)*PW_ + x)*C_ + c8*8;
  }
  const bf16* bbase = WT + (size_t)(nby*BN + srow)*2304 + c8*8;

  float4v acc[4][8];
  #pragma unroll
  for (int jn=0;jn<8;++jn){
    float bvv = bias[nby*BN + wn*128 + jn*16 + l15];
    #pragma unroll
    for (int i=0;i<4;++i){ acc[i][jn][0]=bvv; acc[i][jn][1]=bvv; acc[i][jn][2]=bvv; acc[i][jn][3]=bvv; }
  }

  for (int kt=0; kt<36; ++kt){
    int tap = kt >> 2, kc = (kt & 3) << 6;
    int dy = tap/3, dx = tap - dy*3;
    long ash = (long)(dy*PW_ + dx)*C_ + kc;
    long bsh = (long)kt*64;
    __syncthreads();
    #pragma unroll
    for (int j=0;j<4;++j)
      gl2lds16(Apad + abase[j] + ash, As + (j*256+tid)*8);
    #pragma unroll
    for (int j=0;j<8;++j)
      gl2lds16(bbase + (size_t)j*32*2304 + bsh, Bs + (j*256+tid)*8);
    __syncthreads();
    #pragma unroll
    for (int kk=0; kk<2; ++kk){
      int slot = ((kk<<2) + quad) ^ (l15 & 7);
      short8 af[4], bfr[8];
      #pragma unroll
      for (int jn=0;jn<8;++jn)
        bfr[jn] = *(const short8*)(Bs + (wn*128 + jn*16 + l15)*BK + slot*8);
      #pragma unroll
      for (int i=0;i<4;++i)
        af[i] = *(const short8*)(As + (wm*64 + i*16 + l15)*BK + slot*8);
      #pragma unroll
      for (int i=0;i<4;++i)
        #pragma unroll
        for (int jn=0;jn<8;++jn)
          acc[i][jn] = __builtin_amdgcn_mfma_f32_16x16x32_bf16(af[i], bfr[jn], acc[i][jn], 0,0,0);
    }
  }

  #pragma unroll
  for (int i=0;i<4;++i){
    int mr = bx*BM + wm*64 + i*16 + quad*4;
    #pragma unroll
    for (int jn=0;jn<8;++jn){
      int nc = nby*BN + wn*128 + jn*16 + l15;
      #pragma unroll
      for (int r=0;r<4;++r){
        float v = acc[i][jn][r];
        long m = mr + r;
        if (isval){
          outv[m*256 + nc] = __float2bfloat16(v);
        } else {
          if (nc < 320){
            int h = nc/40, rr = nc - h*40;
            int l = rr >> 3, pxy = rr & 7;
            P[((size_t)l*UNITS_ + m*8 + h)*8 + pxy] = v;
          } else if (nc < 480){
            int hh = (nc-320)/20, ii = (nc-320) - hh*20;
            aw[((size_t)m*8 + hh)*20 + ii] = v;
          }
        }
      }
    }
  }
}

// output conv: N=256 (one by), epilogue writes NCHW f32 directly
__global__ __launch_bounds__(256,2) void gemm_out_k(const bf16* __restrict__ Apad,
                                                    const bf16* __restrict__ WT,
                                                    const float* __restrict__ bias,
                                                    float* __restrict__ out){
  __shared__ __align__(16) bf16 As[BM*BK];
  __shared__ __align__(16) bf16 Bs[BN*BK];
  int tid = threadIdx.x;
  int lane = tid & 63, wvi = tid >> 6;
  int wm = wvi & 1, wn = wvi >> 1;
  int quad = lane >> 4, l15 = lane & 15;
  int bx = blockIdx.x;

  int srow = tid >> 3;
  int c8   = (tid & 7) ^ (srow & 7);
  long abase[4];
  #pragma unroll
  for (int j=0;j<4;++j){
    int p = j*32 + srow;
    int Pm = bx*BM + p;
    int t = Pm / HW_, rem = Pm - t*HW_;
    int y = rem / W_, x = rem - y*W_;
    abase[j] = ((long)(t*PH_ + y)*PW_ + x)*C_ + c8*8;
  }
  const bf16* bbase = WT + (size_t)srow*2304 + c8*8;

  float4v acc[4][8];
  #pragma unroll
  for (int jn=0;jn<8;++jn){
    float bvv = bias[wn*128 + jn*16 + l15];
    #pragma unroll
    for (int i=0;i<4;++i){ acc[i][jn][0]=bvv; acc[i][jn][1]=bvv; acc[i][jn][2]=bvv; acc[i][jn][3]=bvv; }
  }

  for (int kt=0; kt<36; ++kt){
    int tap = kt >> 2, kc = (kt & 3) << 6;
    int dy = tap/3, dx = tap - dy*3;
    long ash = (long)(dy*PW_ + dx)*C_ + kc;
    long bsh = (long)kt*64;
    __syncthreads();
    #pragma unroll
    for (int j=0;j<4;++j)
      gl2lds16(Apad + abase[j] + ash, As + (j*256+tid)*8);
    #pragma unroll
    for (int j=0;j<8;++j)
      gl2lds16(bbase + (size_t)j*32*2304 + bsh, Bs + (j*256+tid)*8);
    __syncthreads();
    #pragma unroll
    for (int kk=0; kk<2; ++kk){
      int slot = ((kk<<2) + quad) ^ (l15 & 7);
      short8 af[4], bfr[8];
      #pragma unroll
      for (int jn=0;jn<8;++jn)
        bfr[jn] = *(const short8*)(Bs + (wn*128 + jn*16 + l15)*BK + slot*8);
      #pragma unroll
      for (int i=0;i<4;++i)
        af[i] = *(const short8*)(As + (wm*64 + i*16 + l15)*BK + slot*8);
      #pragma unroll
      for (int i=0;i<4;++i)
        #pragma unroll
        for (int jn=0;jn<8;++jn)
          acc[i][jn] = __builtin_amdgcn_mfma_f32_16x16x32_bf16(af[i], bfr[jn], acc[i][jn], 0,0,0);
    }
  }

  int t = (bx*BM) / HW_;
  #pragma unroll
  for (int i=0;i<4;++i){
    int m = bx*BM + wm*64 + i*16 + quad*4;
    int pix = m - t*HW_;
    #pragma unroll
    for (int jn=0;jn<8;++jn){
      int nc = wn*128 + jn*16 + l15;
      *(float4v*)(out + ((size_t)(t*C_ + nc))*HW_ + pix) = acc[i][jn];
    }
  }
}

// ---------------------------------------------------------------- prep tab
__device__ const int g_slotTab[25] = {
  -1,  0,  4,  5,  6,
  10, -1,  1,  7,  8,
  13, 11, -1,  2,  9,
  15, 14, 12, -1,  3,
  15, 14, 12, -1,  3 };

// ------------------------------------------ alignment barrier (perf-only)
// Correctness does NOT depend on it: all cross-level data is read-only input.
// Bounded spin -> no deadlock possible. Arrival: device-scope atomicAdd.
// Spin: AGENT-scope atomic load (plain loads can serve stale per-XCD L2).
static __device__ __forceinline__ void align_bar(unsigned* c, unsigned tgt){
  __syncthreads();
  if (threadIdx.x == 0){
    atomicAdd(c, 1u);
    for (int it=0; it<128; ++it){
      if (__hip_atomic_load(c, __ATOMIC_RELAXED, __HIP_MEMORY_SCOPE_AGENT) >= tgt)
        break;
      __builtin_amdgcn_s_sleep(4);
    }
  }
  __syncthreads();
}

// --------------------------------------- fused softmax + sampling, level-outer
// 1920 co-resident blocks (8/CU: 32 VGPR, 12.3 KB LDS), level-lockstep
// ENFORCED by align_bar between levels -> instantaneous gather working set =
// one 3.1 MB value slice per XCD L2. Softmax upfront (kills prep_k + w16);
// acc in registers across levels (kills 4x 31 MB carries).
#define SAMP_BLOCKS 1920
#define GPB 8
__global__ __launch_bounds__(256,8) void samp_k(const unsigned* __restrict__ vb,
                                                const float*   __restrict__ P,
                                                const float*   __restrict__ aw,
                                                const float*   __restrict__ ref,
                                                const float*   __restrict__ flows,
                                                unsigned* __restrict__ ctr,
                                                bf16* __restrict__ attn_pad){
  __shared__ float  sWgt[128][20];
  __shared__ float4 sW[16][4];
  __shared__ int4   sI[16][4];
  int tid = threadIdx.x;
  int u0 = blockIdx.x * (GPB*16);      // 128 units per block

  // upfront softmax for this block's 128 units
  if (tid < 128){
    int unit = u0 + tid;
    const float4* p4 = (const float4*)(aw + (size_t)unit*20);
    float4 v[5];
    #pragma unroll
    for (int i=0;i<5;++i) v[i] = p4[i];
    float* e = (float*)v;
    float m = -1e30f;
    #pragma unroll
    for (int i=0;i<20;++i) m = fmaxf(m, e[i]);
    float s = 0.f;
    #pragma unroll
    for (int i=0;i<20;++i){ e[i] = __expf(e[i]-m); s += e[i]; }
    float inv = 1.f/s;
    #pragma unroll
    for (int i=0;i<20;++i) sWgt[tid][i] = e[i]*inv;
  }

  float a0[GPB], a1[GPB];
  #pragma unroll
  for (int j=0;j<GPB;++j){ a0[j]=0.f; a1[j]=0.f; }

  int g = tid >> 4, e16 = tid & 15;
  int h = g & 7;                       // unit&7 == g&7 (u0,j*16 are mult of 8)

  align_bar(ctr+0, SAMP_BLOCKS);       // align launch front

  for (int l=0; l<NL_; ++l){
    const unsigned* vimg = vb + (size_t)l*HW_*128 + h*16 + e16;
    #pragma unroll
    for (int j=0;j<GPB;++j){
      __syncthreads();                 // prev gather done (covers sWgt 1st time)
      if (tid < 64){
        int gg = tid >> 2, p = tid & 3;
        int unit = u0 + j*16 + gg;
        float2 pr = ((const float2*)P)[((size_t)l*UNITS_ + unit)*4 + p];
        float w = sWgt[j*16+gg][l*4+p];
        int q = unit >> 3;
        int t_q = q / HW_, pix = q - t_q*HW_;
        int slot = g_slotTab[t_q*5 + l];
        float ax = 0.f, ay = 0.f;
        if (slot >= 0){ ax = flows[slot*2*HW_ + pix]; ay = flows[slot*2*HW_ + HW_ + pix]; }
        float ppx = pr.x + ref[(q*5+l)*2+0]*(float)W_ - 0.5f + ax;
        float ppy = pr.y + ref[(q*5+l)*2+1]*(float)H_ - 0.5f + ay;
        float x0f = floorf(ppx), y0f = floorf(ppy);
        float fx = ppx - x0f,    fy = ppy - y0f;
        int x0 = (int)x0f, y0 = (int)y0f;
        int x1 = x0+1, y1 = y0+1;
        float wx0 = 1.f-fx, wx1 = fx, wy0 = 1.f-fy, wy1 = fy;
        if ((unsigned)x0 >= (unsigned)W_) wx0 = 0.f;
        if ((unsigned)x1 >= (unsigned)W_) wx1 = 0.f;
        if ((unsigned)y0 >= (unsigned)H_) wy0 = 0.f;
        if ((unsigned)y1 >= (unsigned)H_) wy1 = 0.f;
        int xc0 = min(max(x0,0),W_-1), xc1 = min(max(x1,0),W_-1);
        int yc0 = min(max(y0,0),H_-1), yc1 = min(max(y1,0),H_-1);
        sW[gg][p] = make_float4(w*wx0*wy0, w*wx1*wy0, w*wx0*wy1, w*wx1*wy1);
        sI[gg][p] = make_int4((yc0*W_+xc0)*128, (yc0*W_+xc1)*128,
                              (yc1*W_+xc0)*128, (yc1*W_+xc1)*128);
      }
      __syncthreads();
      #pragma unroll
      for (int p=0; p<4; ++p){
        float4 w4 = sW[g][p];
        int4   i4 = sI[g][p];
        unsigned u00 = vimg[i4.x], u10 = vimg[i4.y];
        unsigned u01 = vimg[i4.z], u11 = vimg[i4.w];
        union {unsigned v; float f;} lo, hi;
        lo.v = u00<<16; hi.v = u00 & 0xffff0000u;
        a0[j] = fmaf(w4.x, lo.f, a0[j]); a1[j] = fmaf(w4.x, hi.f, a1[j]);
        lo.v = u10<<16; hi.v = u10 & 0xffff0000u;
        a0[j] = fmaf(w4.y, lo.f, a0[j]); a1[j] = fmaf(w4.y, hi.f, a1[j]);
        lo.v = u01<<16; hi.v = u01 & 0xffff0000u;
        a0[j] = fmaf(w4.z, lo.f, a0[j]); a1[j] = fmaf(w4.z, hi.f, a1[j]);
        lo.v = u11<<16; hi.v = u11 & 0xffff0000u;
        a0[j] = fmaf(w4.w, lo.f, a0[j]); a1[j] = fmaf(w4.w, hi.f, a1[j]);
      }
    }
    if (l < NL_-1) align_bar(ctr+1+l, SAMP_BLOCKS);   // level lockstep
  }

  #pragma unroll
  for (int j=0;j<GPB;++j){
    int unit = u0 + j*16 + g;
    int q = unit >> 3;
    int t_q = q / HW_, pix = q - t_q*HW_;
    int yq = pix / W_, xq = pix - yq*W_;
    union {unsigned u; bf16 hh[2];} pk;
    pk.hh[0] = __float2bfloat16(a0[j]);
    pk.hh[1] = __float2bfloat16(a1[j]);
    *(unsigned*)(attn_pad + (((size_t)t_q*PH_ + yq+1)*PW_ + xq+1)*C_ + h*DH_ + e16*2) = pk.u;
  }
}

// ---------------------------------------------------------------- launcher
extern "C" void kernel_launch(void* const* d_in, const int* in_sizes, int n_in,
                              void* d_out, int out_size, void* d_ws, size_t ws_size,
                              hipStream_t stream) {
  const float* query   = (const float*)d_in[0];
  const float* in_flat = (const float*)d_in[1];
  const float* refpts  = (const float*)d_in[2];
  const float* ff      = (const float*)d_in[6];
  const float* fb      = (const float*)d_in[7];
  const float* w_off   = (const float*)d_in[8];
  const float* b_off   = (const float*)d_in[9];
  const float* w_attn  = (const float*)d_in[10];
  const float* b_attn  = (const float*)d_in[11];
  const float* w_val   = (const float*)d_in[12];
  const float* b_val   = (const float*)d_in[13];
  const float* w_out   = (const float*)d_in[14];
  const float* b_out   = (const float*)d_in[15];
  float* out = (float*)d_out;

  // ---- memory map ----
  char* ws = (char*)d_ws;
  bf16*  v_pad   = (bf16*) (ws + 0);            // 16,558,080  in_flat pad -> attn_pad
  bf16*  q_pad   = (bf16*) (ws + 16558080);     // 16,558,080
  bf16*  v_val   = (bf16*) (ws + 33116160);     // 15,728,640  gather source
  float* P       = (float*)(ws + 48844800);     // 39,321,600  [5][UNITS][4][2] f32 raw
  float* v_aw    = (float*)(ws + 88166400);     // 19,660,800  raw attn logits
  float* v_flows = (float*)(ws + 107827200);    //    786,432
  bf16*  WT_val  = (bf16*) (ws + 108613632);    //  1,179,648
  bf16*  WT_oa   = (bf16*) (ws + 109793280);    //  2,359,296
  bf16*  WT_out  = (bf16*) (ws + 112152576);    //  1,179,648
  float* bias_oa = (float*)(ws + 113332224);    //      2,048
  unsigned* ctr  = (unsigned*)(ws + 113334272); //         64  -> end 113,334,336
  bf16*  attn_pad = v_pad;
  if (ws_size < (size_t)113334336) return;

  // mega prologue: pad+cast, weight transpose, flow init, flow A, border zero
  mega0_k<<<MG_PAD+MG_WT+MG_INIT+MG_FA+MG_BZ, 256, 0, stream>>>(
      in_flat, query, v_pad, q_pad,
      w_val, w_off, w_attn, w_out, b_off, b_attn,
      WT_val, WT_oa, WT_out, bias_oa, ctr, ff, fb, v_flows);

  // flow compose stages B+C
  flowBC_k<<<dim3(HW_/256, 3), 256, 0, stream>>>(ff, fb, v_flows);

  // fused val+oa conv-GEMM (240 x 3 blocks)
  gemm12_k<<<dim3(240, 3), 256, 0, stream>>>(v_pad, q_pad, WT_val, WT_oa,
                                             b_val, bias_oa, v_val, P, v_aw);

  // fused softmax + 5-level sampling, barrier-enforced level lockstep
  samp_k<<<SAMP_BLOCKS, 256, 0, stream>>>((const unsigned*)v_val, P, v_aw,
                                          refpts, v_flows, ctr, attn_pad);

  // output conv, direct NCHW f32 epilogue
  gemm_out_k<<<dim3(240, 1), 256, 0, stream>>>(attn_pad, WT_out, b_out, out);
}

// Round 7
// 446.087 us; speedup vs baseline: 2.7907x; 2.7907x over previous
//
#include <hip/hip_runtime.h>
#include <hip/hip_bf16.h>
#include <hip/hip_fp16.h>

typedef __hip_bfloat16 bf16;
typedef __attribute__((ext_vector_type(8))) short short8;
typedef __attribute__((ext_vector_type(4))) float float4v;

#define T_  5
#define H_  64
#define W_  96
#define HW_ (H_*W_)
#define C_  256
#define NH_ 8
#define DH_ 32
#define NL_ 5
#define NP_ 4
#define LQ_ (T_*HW_)
#define UNITS_ (LQ_*NH_)          // 245760

// padded geometry: [T][66][98][256] bf16
#define PH_ 66
#define PW_ 98

static __device__ __forceinline__ void gl2lds16(const bf16* g, bf16* l){
  __builtin_amdgcn_global_load_lds(
      (const __attribute__((address_space(1))) unsigned int*)g,
      (__attribute__((address_space(3))) unsigned int*)l, 16, 0, 0);
}

// ------------------------------------------------------- bilinear (zero pad)
static __device__ __forceinline__ float bilin2(const float* __restrict__ img,
                                               float px, float py){
  float x0f = floorf(px), y0f = floorf(py);
  int x0 = (int)x0f, y0 = (int)y0f;
  float fx = px - x0f, fy = py - y0f;
  int x1 = x0+1, y1 = y0+1;
  bool vx0 = (x0>=0)&&(x0<W_), vx1 = (x1>=0)&&(x1<W_);
  bool vy0 = (y0>=0)&&(y0<H_), vy1 = (y1>=0)&&(y1<H_);
  float c00 = (vx0&&vy0)? img[y0*W_+x0] : 0.f;
  float c10 = (vx1&&vy0)? img[y0*W_+x1] : 0.f;
  float c01 = (vx0&&vy1)? img[y1*W_+x0] : 0.f;
  float c11 = (vx1&&vy1)? img[y1*W_+x1] : 0.f;
  return c00*(1.f-fx)*(1.f-fy) + c10*fx*(1.f-fy) + c01*(1.f-fx)*fy + c11*fx*fy;
}

// ------------------------------------------------------------- mega prologue
#define MG_PAD   960
#define MG_WT    1025
#define MG_INIT  336
#define MG_FA    120
#define MG_BZ    405
__global__ __launch_bounds__(256) void mega0_k(
    const float* __restrict__ in0, const float* __restrict__ in1,
    bf16* __restrict__ pad0, bf16* __restrict__ pad1,
    const float* __restrict__ wv, const float* __restrict__ wo,
    const float* __restrict__ wa, const float* __restrict__ wout,
    const float* __restrict__ bo, const float* __restrict__ ba,
    bf16* __restrict__ WTv, bf16* __restrict__ WToa, bf16* __restrict__ WTout,
    float* __restrict__ boa,
    const float* __restrict__ ff, const float* __restrict__ fb,
    float* __restrict__ flows)
{
  __shared__ __align__(16) char smem[33792];
  int b = blockIdx.x, tid = threadIdx.x;
  if (b < MG_PAD){
    bf16 (*sb)[66] = (bf16(*)[66])smem;
    int z = b / 480, r = b - z*480;
    int t = r / 96, bxp = r - t*96;
    const float* in = z ? in1 : in0;
    bf16* pad       = z ? pad1 : pad0;
    int pix0 = bxp*64;
    int pl = tid & 63, cg = tid >> 6;
    #pragma unroll 4
    for (int it=0; it<64; ++it){
      int c = it*4 + cg;
      sb[c][pl] = __float2bfloat16(in[((size_t)t*C_ + c)*HW_ + pix0 + pl]);
    }
    __syncthreads();
    for (int p=0; p<64; ++p){
      int pix = pix0 + p;
      int y = pix/W_, x = pix - y*W_;
      pad[(((size_t)t*PH_ + y+1)*PW_ + x+1)*C_ + tid] = sb[tid][p];
    }
    return;
  }
  b -= MG_PAD;
  if (b < MG_WT){
    if (b == 1024){
      #pragma unroll
      for (int k=0;k<2;++k){
        int n = tid + k*256;
        float v = 0.f;
        if (n < 320) v = bo[n]; else if (n < 480) v = ba[n-320];
        boa[n] = v;
      }
      return;
    }
    float* ld = (float*)smem;
    const float* src; bf16* dst;
    if (b < 256){ src = wv + (size_t)b*2304; dst = WTv + (size_t)b*2304; }
    else if (b < 768){
      int n = b-256; dst = WToa + (size_t)n*2304;
      src = (n<320) ? (wo + (size_t)n*2304)
          : ((n<480) ? (wa + (size_t)(n-320)*2304) : (const float*)0);
    } else { int n = b-768; src = wout + (size_t)n*2304; dst = WTout + (size_t)n*2304; }
    if (src){
      #pragma unroll
      for (int k=0;k<9;++k) ld[tid + k*256] = src[tid + k*256];
      __syncthreads();
      #pragma unroll
      for (int k=0;k<9;++k){
        int o = tid + k*256; int tap = o >> 8, ci = o & 255;
        dst[o] = __float2bfloat16(ld[ci*9 + tap]);
      }
    } else {
      #pragma unroll
      for (int k=0;k<9;++k) dst[tid + k*256] = __float2bfloat16(0.f);
    }
    return;
  }
  b -= MG_WT;
  if (b < MG_INIT){
    int i = b*256 + tid;            // < 86016
    const int per = 2*HW_;
    int f = i/per, r = i - f*per;
    if (f < 4) flows[f*per + r]          = ff[i];
    else       flows[(10+(f-4))*per + r] = fb[(f-4)*per + r];
    return;
  }
  b -= MG_INIT;
  if (b < MG_FA){
    int ci = b / 24;
    int pix = (b - ci*24)*256 + tid;
    const int dsts[5] = {4,7,9,13,14};
    const float* A; const float* S;
    switch(ci){
      case 0: A = ff;          S = ff + 2*HW_; break;
      case 1: A = ff + 2*HW_;  S = ff + 4*HW_; break;
      case 2: A = ff + 4*HW_;  S = ff + 6*HW_; break;
      case 3: A = fb + 2*HW_;  S = fb;         break;
      default:A = fb + 4*HW_;  S = fb + 2*HW_; break;
    }
    float* D = flows + dsts[ci]*2*HW_;
    float ax = A[pix], ay = A[HW_+pix];
    float px = (float)(pix % W_) + ax;
    float py = (float)(pix / W_) + ay;
    D[pix]      = ax + bilin2(S,      px, py);
    D[HW_+pix]  = ay + bilin2(S+HW_,  px, py);
    return;
  }
  b -= MG_FA;
  {
    int idx = b*256 + tid;          // < 103680 exactly
    int pair = idx / 10368, r = idx - pair*10368;
    int pxi = r >> 5, q8 = r & 31;
    int t = pair >> 1, z = pair & 1;
    int y, x;
    if (pxi < 98){ y = 0;  x = pxi; }
    else if (pxi < 196){ y = 65; x = pxi-98; }
    else if (pxi < 260){ y = pxi-196+1; x = 0; }
    else { y = pxi-260+1; x = 97; }
    bf16* pad = z ? pad1 : pad0;
    uint4 zz; zz.x = zz.y = zz.z = zz.w = 0u;
    *(uint4*)(pad + (((size_t)t*PH_ + y)*PW_ + x)*C_ + q8*8) = zz;
  }
}

// ----------------------------------------------------------- implicit GEMM
// R0-verified structure: BM=128, BN=256, BK=64, 4 waves, wave tile 64x128,
// 48 KB LDS -> 2 blocks/CU. Frozen (R1/R4 pipelining neutral; R5/R6 fused
// sampler falsified both ways). Extra blocks bx>=240 run flowBC (depends
// only on mega0; feeds only prep/phases which launch later).
#define BM 128
#define BN 256
#define BK 64

// fused val (byy 0, N=256) + oa (byy 1..2, N=512) conv-GEMM  + flowBC tail
__global__ __launch_bounds__(256,2) void gemm12_k(const bf16* __restrict__ Av,
                                                  const bf16* __restrict__ Aq,
                                                  const bf16* __restrict__ WTv,
                                                  const bf16* __restrict__ WToa,
                                                  const float* __restrict__ bv,
                                                  const float* __restrict__ boa,
                                                  bf16* __restrict__ outv,
                                                  float* __restrict__ P,
                                                  float* __restrict__ aw,
                                                  const float* __restrict__ ff,
                                                  const float* __restrict__ fb,
                                                  float* __restrict__ flows){
  __shared__ __align__(16) bf16 As[BM*BK];   // 16 KB
  __shared__ __align__(16) bf16 Bs[BN*BK];   // 32 KB
  int tid = threadIdx.x;
  int bx = blockIdx.x, byy = blockIdx.y;

  if (bx >= 240){
    // -------- flow compose stages B + C (72 rider blocks) --------
    int gy = byy;
    int pix = (bx-240)*256 + tid;
    float gx = (float)(pix % W_), gyy = (float)(pix / W_);
    if (gy == 0){
      const float* A   = flows + 4*2*HW_;
      const float* S23 = ff + 4*HW_;
      const float* S34 = ff + 6*HW_;
      float ax = A[pix], ay = A[HW_+pix];
      float px = gx + ax, py = gyy + ay;
      float c3x = ax + bilin2(S23,      px, py);
      float c3y = ay + bilin2(S23+HW_,  px, py);
      float* D3 = flows + 5*2*HW_;
      D3[pix] = c3x; D3[HW_+pix] = c3y;
      px = gx + c3x; py = gyy + c3y;
      float* D4 = flows + 6*2*HW_;
      D4[pix]     = c3x + bilin2(S34,     px, py);
      D4[HW_+pix] = c3y + bilin2(S34+HW_, px, py);
    } else if (gy == 1){
      const float* A = flows + 7*2*HW_;
      const float* S = ff + 6*HW_;
      float ax = A[pix], ay = A[HW_+pix];
      float px = gx + ax, py = gyy + ay;
      float* D = flows + 8*2*HW_;
      D[pix]     = ax + bilin2(S,     px, py);
      D[HW_+pix] = ay + bilin2(S+HW_, px, py);
    } else {
      const float* A = flows + 14*2*HW_;
      const float* S = fb;
      float ax = A[pix], ay = A[HW_+pix];
      float px = gx + ax, py = gyy + ay;
      float* D = flows + 15*2*HW_;
      D[pix]     = ax + bilin2(S,     px, py);
      D[HW_+pix] = ay + bilin2(S+HW_, px, py);
    }
    return;
  }

  int lane = tid & 63, wvi = tid >> 6;
  int wm = wvi & 1, wn = wvi >> 1;
  int quad = lane >> 4, l15 = lane & 15;
  bool isval = byy == 0;
  const bf16* Apad  = isval ? Av  : Aq;
  const bf16* WT    = isval ? WTv : WToa;
  const float* bias = isval ? bv  : boa;
  int nby = isval ? 0 : byy - 1;

  int srow = tid >> 3;
  int c8   = (tid & 7) ^ (srow & 7);
  long abase[4];
  #pragma unroll
  for (int j=0;j<4;++j){
    int p = j*32 + srow;
    int Pm = bx*BM + p;
    int t = Pm / HW_, rem = Pm - t*HW_;
    int y = rem / W_, x = rem - y*W_;
    abase[j] = ((long)(t*PH_ + y)*PW_ + x)*C_ + c8*8;
  }
  const bf16* bbase = WT + (size_t)(nby*BN + srow)*2304 + c8*8;

  float4v acc[4][8];
  #pragma unroll
  for (int jn=0;jn<8;++jn){
    float bvv = bias[nby*BN + wn*128 + jn*16 + l15];
    #pragma unroll
    for (int i=0;i<4;++i){ acc[i][jn][0]=bvv; acc[i][jn][1]=bvv; acc[i][jn][2]=bvv; acc[i][jn][3]=bvv; }
  }

  for (int kt=0; kt<36; ++kt){
    int tap = kt >> 2, kc = (kt & 3) << 6;
    int dy = tap/3, dx = tap - dy*3;
    long ash = (long)(dy*PW_ + dx)*C_ + kc;
    long bsh = (long)kt*64;
    __syncthreads();
    #pragma unroll
    for (int j=0;j<4;++j)
      gl2lds16(Apad + abase[j] + ash, As + (j*256+tid)*8);
    #pragma unroll
    for (int j=0;j<8;++j)
      gl2lds16(bbase + (size_t)j*32*2304 + bsh, Bs + (j*256+tid)*8);
    __syncthreads();
    #pragma unroll
    for (int kk=0; kk<2; ++kk){
      int slot = ((kk<<2) + quad) ^ (l15 & 7);
      short8 af[4], bfr[8];
      #pragma unroll
      for (int jn=0;jn<8;++jn)
        bfr[jn] = *(const short8*)(Bs + (wn*128 + jn*16 + l15)*BK + slot*8);
      #pragma unroll
      for (int i=0;i<4;++i)
        af[i] = *(const short8*)(As + (wm*64 + i*16 + l15)*BK + slot*8);
      #pragma unroll
      for (int i=0;i<4;++i)
        #pragma unroll
        for (int jn=0;jn<8;++jn)
          acc[i][jn] = __builtin_amdgcn_mfma_f32_16x16x32_bf16(af[i], bfr[jn], acc[i][jn], 0,0,0);
    }
  }

  #pragma unroll
  for (int i=0;i<4;++i){
    int mr = bx*BM + wm*64 + i*16 + quad*4;
    #pragma unroll
    for (int jn=0;jn<8;++jn){
      int nc = nby*BN + wn*128 + jn*16 + l15;
      #pragma unroll
      for (int r=0;r<4;++r){
        float v = acc[i][jn][r];
        long m = mr + r;
        if (isval){
          outv[m*256 + nc] = __float2bfloat16(v);
        } else {
          if (nc < 320){
            int h = nc/40, rr = nc - h*40;
            int l = rr >> 3, pxy = rr & 7;
            P[((size_t)l*UNITS_ + m*8 + h)*8 + pxy] = v;
          } else if (nc < 480){
            int hh = (nc-320)/20, ii = (nc-320) - hh*20;
            aw[((size_t)m*8 + hh)*20 + ii] = v;
          }
        }
      }
    }
  }
}

// output conv: N=256 (one by), epilogue writes NCHW f32 directly
__global__ __launch_bounds__(256,2) void gemm_out_k(const bf16* __restrict__ Apad,
                                                    const bf16* __restrict__ WT,
                                                    const float* __restrict__ bias,
                                                    float* __restrict__ out){
  __shared__ __align__(16) bf16 As[BM*BK];
  __shared__ __align__(16) bf16 Bs[BN*BK];
  int tid = threadIdx.x;
  int lane = tid & 63, wvi = tid >> 6;
  int wm = wvi & 1, wn = wvi >> 1;
  int quad = lane >> 4, l15 = lane & 15;
  int bx = blockIdx.x;

  int srow = tid >> 3;
  int c8   = (tid & 7) ^ (srow & 7);
  long abase[4];
  #pragma unroll
  for (int j=0;j<4;++j){
    int p = j*32 + srow;
    int Pm = bx*BM + p;
    int t = Pm / HW_, rem = Pm - t*HW_;
    int y = rem / W_, x = rem - y*W_;
    abase[j] = ((long)(t*PH_ + y)*PW_ + x)*C_ + c8*8;
  }
  const bf16* bbase = WT + (size_t)srow*2304 + c8*8;

  float4v acc[4][8];
  #pragma unroll
  for (int jn=0;jn<8;++jn){
    float bvv = bias[wn*128 + jn*16 + l15];
    #pragma unroll
    for (int i=0;i<4;++i){ acc[i][jn][0]=bvv; acc[i][jn][1]=bvv; acc[i][jn][2]=bvv; acc[i][jn][3]=bvv; }
  }

  for (int kt=0; kt<36; ++kt){
    int tap = kt >> 2, kc = (kt & 3) << 6;
    int dy = tap/3, dx = tap - dy*3;
    long ash = (long)(dy*PW_ + dx)*C_ + kc;
    long bsh = (long)kt*64;
    __syncthreads();
    #pragma unroll
    for (int j=0;j<4;++j)
      gl2lds16(Apad + abase[j] + ash, As + (j*256+tid)*8);
    #pragma unroll
    for (int j=0;j<8;++j)
      gl2lds16(bbase + (size_t)j*32*2304 + bsh, Bs + (j*256+tid)*8);
    __syncthreads();
    #pragma unroll
    for (int kk=0; kk<2; ++kk){
      int slot = ((kk<<2) + quad) ^ (l15 & 7);
      short8 af[4], bfr[8];
      #pragma unroll
      for (int jn=0;jn<8;++jn)
        bfr[jn] = *(const short8*)(Bs + (wn*128 + jn*16 + l15)*BK + slot*8);
      #pragma unroll
      for (int i=0;i<4;++i)
        af[i] = *(const short8*)(As + (wm*64 + i*16 + l15)*BK + slot*8);
      #pragma unroll
      for (int i=0;i<4;++i)
        #pragma unroll
        for (int jn=0;jn<8;++jn)
          acc[i][jn] = __builtin_amdgcn_mfma_f32_16x16x32_bf16(af[i], bfr[jn], acc[i][jn], 0,0,0);
    }
  }

  int t = (bx*BM) / HW_;
  #pragma unroll
  for (int i=0;i<4;++i){
    int m = bx*BM + wm*64 + i*16 + quad*4;
    int pix = m - t*HW_;
    #pragma unroll
    for (int jn=0;jn<8;++jn){
      int nc = wn*128 + jn*16 + l15;
      *(float4v*)(out + ((size_t)(t*C_ + nc))*HW_ + pix) = acc[i][jn];
    }
  }
}

// ---------------------------------------------------------------- prep tab
__device__ const int g_slotTab[25] = {
  -1,  0,  4,  5,  6,
  10, -1,  1,  7,  8,
  13, 11, -1,  2,  9,
  15, 14, 12, -1,  3,
  15, 14, 12, -1,  3 };

// per unit: softmax(aw) -> w16
__global__ __launch_bounds__(256) void prep_k(const float* __restrict__ aw,
                                              __half* __restrict__ w16){
  int unit = blockIdx.x*256 + threadIdx.x;    // 245760 total
  const float4* p4 = (const float4*)(aw + (size_t)unit*20);
  float4 v[5];
  #pragma unroll
  for (int i=0;i<5;++i) v[i] = p4[i];
  float* e = (float*)v;
  float m = -1e30f;
  #pragma unroll
  for (int i=0;i<20;++i) m = fmaxf(m, e[i]);
  float s = 0.f;
  #pragma unroll
  for (int i=0;i<20;++i){ e[i] = __expf(e[i]-m); s += e[i]; }
  float inv = 1.f/s;
  __half2* o2 = (__half2*)(w16 + (size_t)unit*20);
  #pragma unroll
  for (int i=0;i<10;++i)
    o2[i] = __floats2half2_rn(e[2*i]*inv, e[2*i+1]*inv);
}

// ------------------------------------------------------- per-level sampling
template<bool FIRST, bool LAST>
__global__ __launch_bounds__(256) void phase_k(const unsigned* __restrict__ vimg0,
                                               const float2*  __restrict__ Pl,
                                               const __half*  __restrict__ wl,
                                               const float*   __restrict__ ref,
                                               const float*   __restrict__ flows,
                                               int lvl,
                                               __half2* __restrict__ acc,
                                               bf16* __restrict__ attn_pad){
  __shared__ float4 sW[16][4];
  __shared__ int4   sI[16][4];
  int tid = threadIdx.x;
  if (tid < 64){
    int g = tid >> 2, p = tid & 3;
    int unit = blockIdx.x*16 + g;
    float2 pr = Pl[(size_t)unit*4 + p];
    float w = __half2float(wl[(size_t)unit*20 + p]);
    int q = unit >> 3;
    int t_q = q / HW_, pix = q - t_q*HW_;
    int slot = g_slotTab[t_q*5 + lvl];
    float ax = 0.f, ay = 0.f;
    if (slot >= 0){ ax = flows[slot*2*HW_ + pix]; ay = flows[slot*2*HW_ + HW_ + pix]; }
    float ppx = pr.x + ref[(q*5+lvl)*2+0]*(float)W_ - 0.5f + ax;
    float ppy = pr.y + ref[(q*5+lvl)*2+1]*(float)H_ - 0.5f + ay;
    float x0f = floorf(ppx), y0f = floorf(ppy);
    float fx = ppx - x0f,    fy = ppy - y0f;
    int x0 = (int)x0f, y0 = (int)y0f;
    int x1 = x0+1, y1 = y0+1;
    float wx0 = 1.f-fx, wx1 = fx, wy0 = 1.f-fy, wy1 = fy;
    if ((unsigned)x0 >= (unsigned)W_) wx0 = 0.f;
    if ((unsigned)x1 >= (unsigned)W_) wx1 = 0.f;
    if ((unsigned)y0 >= (unsigned)H_) wy0 = 0.f;
    if ((unsigned)y1 >= (unsigned)H_) wy1 = 0.f;
    int xc0 = min(max(x0,0),W_-1), xc1 = min(max(x1,0),W_-1);
    int yc0 = min(max(y0,0),H_-1), yc1 = min(max(y1,0),H_-1);
    sW[g][p] = make_float4(w*wx0*wy0, w*wx1*wy0, w*wx0*wy1, w*wx1*wy1);
    sI[g][p] = make_int4((yc0*W_+xc0)*128, (yc0*W_+xc1)*128,
                         (yc1*W_+xc0)*128, (yc1*W_+xc1)*128);
  }
  __syncthreads();
  int g = tid >> 4, e = tid & 15;
  int unit = blockIdx.x*16 + g;
  int q = unit >> 3, h = unit & 7;
  const unsigned* vimg = vimg0 + h*16 + e;
  float a0, a1;
  if (FIRST){ a0 = 0.f; a1 = 0.f; }
  else { __half2 c = acc[(size_t)unit*16 + e]; a0 = __low2float(c); a1 = __high2float(c); }
  #pragma unroll
  for (int p=0; p<4; ++p){
    float4 w4 = sW[g][p];
    int4   i4 = sI[g][p];
    unsigned u00 = vimg[i4.x], u10 = vimg[i4.y];
    unsigned u01 = vimg[i4.z], u11 = vimg[i4.w];
    union {unsigned v; float f;} lo, hi;
    lo.v = u00<<16; hi.v = u00 & 0xffff0000u;
    a0 = fmaf(w4.x, lo.f, a0); a1 = fmaf(w4.x, hi.f, a1);
    lo.v = u10<<16; hi.v = u10 & 0xffff0000u;
    a0 = fmaf(w4.y, lo.f, a0); a1 = fmaf(w4.y, hi.f, a1);
    lo.v = u01<<16; hi.v = u01 & 0xffff0000u;
    a0 = fmaf(w4.z, lo.f, a0); a1 = fmaf(w4.z, hi.f, a1);
    lo.v = u11<<16; hi.v = u11 & 0xffff0000u;
    a0 = fmaf(w4.w, lo.f, a0); a1 = fmaf(w4.w, hi.f, a1);
  }
  if (LAST){
    int t_q = q / HW_, pix = q - t_q*HW_;
    int yq = pix / W_, xq = pix - yq*W_;
    union {unsigned u; bf16 hh[2];} pk;
    pk.hh[0] = __float2bfloat16(a0);
    pk.hh[1] = __float2bfloat16(a1);
    *(unsigned*)(attn_pad + (((size_t)t_q*PH_ + yq+1)*PW_ + xq+1)*C_ + h*DH_ + e*2) = pk.u;
  } else {
    acc[(size_t)unit*16 + e] = __floats2half2_rn(a0, a1);
  }
}

// ---------------------------------------------------------------- launcher
extern "C" void kernel_launch(void* const* d_in, const int* in_sizes, int n_in,
                              void* d_out, int out_size, void* d_ws, size_t ws_size,
                              hipStream_t stream) {
  const float* query   = (const float*)d_in[0];
  const float* in_flat = (const float*)d_in[1];
  const float* refpts  = (const float*)d_in[2];
  const float* ff      = (const float*)d_in[6];
  const float* fb      = (const float*)d_in[7];
  const float* w_off   = (const float*)d_in[8];
  const float* b_off   = (const float*)d_in[9];
  const float* w_attn  = (const float*)d_in[10];
  const float* b_attn  = (const float*)d_in[11];
  const float* w_val   = (const float*)d_in[12];
  const float* b_val   = (const float*)d_in[13];
  const float* w_out   = (const float*)d_in[14];
  const float* b_out   = (const float*)d_in[15];
  float* out = (float*)d_out;

  // ---- memory map (peak 113,334,272 B) ----
  char* ws = (char*)d_ws;
  bf16*  v_pad   = (bf16*) (ws + 0);            // 16,558,080  in_flat pad -> attn_pad
  bf16*  q_pad   = (bf16*) (ws + 16558080);     // 16,558,080  (dead after gemm12)
  __half* w16    = (__half*)(ws + 16558080);    //  9,830,400  (late, over dead q_pad)
  bf16*  v_val   = (bf16*) (ws + 33116160);     // 15,728,640  gather source
  float* P       = (float*)(ws + 48844800);     // 39,321,600  [5][UNITS][4][2] f32 raw
  float* v_aw    = (float*)(ws + 88166400);     // 19,660,800  (dead after prep)
  __half2* acc   = (__half2*)(ws + 88166400);   // 15,728,640  (late, over dead v_aw)
  float* v_flows = (float*)(ws + 107827200);    //    786,432
  bf16*  WT_val  = (bf16*) (ws + 108613632);    //  1,179,648
  bf16*  WT_oa   = (bf16*) (ws + 109793280);    //  2,359,296
  bf16*  WT_out  = (bf16*) (ws + 112152576);    //  1,179,648
  float* bias_oa = (float*)(ws + 113332224);    //      2,048  -> end 113,334,272
  bf16*  attn_pad = v_pad;
  if (ws_size < (size_t)113334272) return;

  // mega prologue: pad+cast, weight transpose, flow init, flow A, border zero
  mega0_k<<<MG_PAD+MG_WT+MG_INIT+MG_FA+MG_BZ, 256, 0, stream>>>(
      in_flat, query, v_pad, q_pad,
      w_val, w_off, w_attn, w_out, b_off, b_attn,
      WT_val, WT_oa, WT_out, bias_oa, ff, fb, v_flows);

  // fused val+oa conv-GEMM (240 x 3 blocks) + flowBC rider blocks (24 x 3)
  gemm12_k<<<dim3(264, 3), 256, 0, stream>>>(v_pad, q_pad, WT_val, WT_oa,
                                             b_val, bias_oa, v_val, P, v_aw,
                                             ff, fb, v_flows);

  // softmax only
  prep_k<<<UNITS_/256, 256, 0, stream>>>(v_aw, w16);

  // per-level sampling phases (L2-resident gather slices, half2 carry)
  {
    const unsigned* vb = (const unsigned*)v_val;
    phase_k<true ,false><<<UNITS_/16, 256, 0, stream>>>(vb + 0ul*HW_*128,
        (const float2*)(P + 0ul*UNITS_*8), w16 + 0,  refpts, v_flows, 0, acc, attn_pad);
    phase_k<false,false><<<UNITS_/16, 256, 0, stream>>>(vb + 1ul*HW_*128,
        (const float2*)(P + 1ul*UNITS_*8), w16 + 4,  refpts, v_flows, 1, acc, attn_pad);
    phase_k<false,false><<<UNITS_/16, 256, 0, stream>>>(vb + 2ul*HW_*128,
        (const float2*)(P + 2ul*UNITS_*8), w16 + 8,  refpts, v_flows, 2, acc, attn_pad);
    phase_k<false,false><<<UNITS_/16, 256, 0, stream>>>(vb + 3ul*HW_*128,
        (const float2*)(P + 3ul*UNITS_*8), w16 + 12, refpts, v_flows, 3, acc, attn_pad);
    phase_k<false,true ><<<UNITS_/16, 256, 0, stream>>>(vb + 4ul*HW_*128,
        (const float2*)(P + 4ul*UNITS_*8), w16 + 16, refpts, v_flows, 4, acc, attn_pad);
  }

  // output conv, direct NCHW f32 epilogue
  gemm_out_k<<<dim3(240, 1), 256, 0, stream>>>(attn_pad, WT_out, b_out, out);
}

// Round 8
// 444.868 us; speedup vs baseline: 2.7984x; 1.0027x over previous
//
#include <hip/hip_runtime.h>
#include <hip/hip_bf16.h>
#include <hip/hip_fp16.h>

typedef __hip_bfloat16 bf16;
typedef __attribute__((ext_vector_type(8))) short short8;
typedef __attribute__((ext_vector_type(4))) float float4v;

#define T_  5
#define H_  64
#define W_  96
#define HW_ (H_*W_)
#define C_  256
#define NH_ 8
#define DH_ 32
#define NL_ 5
#define NP_ 4
#define LQ_ (T_*HW_)
#define UNITS_ (LQ_*NH_)          // 245760

// padded geometry: [T][66][98][256] bf16
#define PH_ 66
#define PW_ 98

static __device__ __forceinline__ void gl2lds16(const bf16* g, bf16* l){
  __builtin_amdgcn_global_load_lds(
      (const __attribute__((address_space(1))) unsigned int*)g,
      (__attribute__((address_space(3))) unsigned int*)l, 16, 0, 0);
}

// ------------------------------------------------------- bilinear (zero pad)
static __device__ __forceinline__ float bilin2(const float* __restrict__ img,
                                               float px, float py){
  float x0f = floorf(px), y0f = floorf(py);
  int x0 = (int)x0f, y0 = (int)y0f;
  float fx = px - x0f, fy = py - y0f;
  int x1 = x0+1, y1 = y0+1;
  bool vx0 = (x0>=0)&&(x0<W_), vx1 = (x1>=0)&&(x1<W_);
  bool vy0 = (y0>=0)&&(y0<H_), vy1 = (y1>=0)&&(y1<H_);
  float c00 = (vx0&&vy0)? img[y0*W_+x0] : 0.f;
  float c10 = (vx1&&vy0)? img[y0*W_+x1] : 0.f;
  float c01 = (vx0&&vy1)? img[y1*W_+x0] : 0.f;
  float c11 = (vx1&&vy1)? img[y1*W_+x1] : 0.f;
  return c00*(1.f-fx)*(1.f-fy) + c10*fx*(1.f-fy) + c01*(1.f-fx)*fy + c11*fx*fy;
}

// ------------------------------------------------------------- mega prologue
#define MG_PAD   960
#define MG_WT    1025
#define MG_INIT  336
#define MG_FA    120
#define MG_BZ    405
__global__ __launch_bounds__(256) void mega0_k(
    const float* __restrict__ in0, const float* __restrict__ in1,
    bf16* __restrict__ pad0, bf16* __restrict__ pad1,
    const float* __restrict__ wv, const float* __restrict__ wo,
    const float* __restrict__ wa, const float* __restrict__ wout,
    const float* __restrict__ bo, const float* __restrict__ ba,
    bf16* __restrict__ WTv, bf16* __restrict__ WToa, bf16* __restrict__ WTout,
    float* __restrict__ boa,
    const float* __restrict__ ff, const float* __restrict__ fb,
    float* __restrict__ flows)
{
  __shared__ __align__(16) char smem[33792];
  int b = blockIdx.x, tid = threadIdx.x;
  if (b < MG_PAD){
    bf16 (*sb)[66] = (bf16(*)[66])smem;
    int z = b / 480, r = b - z*480;
    int t = r / 96, bxp = r - t*96;
    const float* in = z ? in1 : in0;
    bf16* pad       = z ? pad1 : pad0;
    int pix0 = bxp*64;
    int pl = tid & 63, cg = tid >> 6;
    #pragma unroll 4
    for (int it=0; it<64; ++it){
      int c = it*4 + cg;
      sb[c][pl] = __float2bfloat16(in[((size_t)t*C_ + c)*HW_ + pix0 + pl]);
    }
    __syncthreads();
    for (int p=0; p<64; ++p){
      int pix = pix0 + p;
      int y = pix/W_, x = pix - y*W_;
      pad[(((size_t)t*PH_ + y+1)*PW_ + x+1)*C_ + tid] = sb[tid][p];
    }
    return;
  }
  b -= MG_PAD;
  if (b < MG_WT){
    if (b == 1024){
      #pragma unroll
      for (int k=0;k<2;++k){
        int n = tid + k*256;
        float v = 0.f;
        if (n < 320) v = bo[n]; else if (n < 480) v = ba[n-320];
        boa[n] = v;
      }
      return;
    }
    float* ld = (float*)smem;
    const float* src; bf16* dst;
    if (b < 256){ src = wv + (size_t)b*2304; dst = WTv + (size_t)b*2304; }
    else if (b < 768){
      int n = b-256; dst = WToa + (size_t)n*2304;
      src = (n<320) ? (wo + (size_t)n*2304)
          : ((n<480) ? (wa + (size_t)(n-320)*2304) : (const float*)0);
    } else { int n = b-768; src = wout + (size_t)n*2304; dst = WTout + (size_t)n*2304; }
    if (src){
      #pragma unroll
      for (int k=0;k<9;++k) ld[tid + k*256] = src[tid + k*256];
      __syncthreads();
      #pragma unroll
      for (int k=0;k<9;++k){
        int o = tid + k*256; int tap = o >> 8, ci = o & 255;
        dst[o] = __float2bfloat16(ld[ci*9 + tap]);
      }
    } else {
      #pragma unroll
      for (int k=0;k<9;++k) dst[tid + k*256] = __float2bfloat16(0.f);
    }
    return;
  }
  b -= MG_WT;
  if (b < MG_INIT){
    int i = b*256 + tid;            // < 86016
    const int per = 2*HW_;
    int f = i/per, r = i - f*per;
    if (f < 4) flows[f*per + r]          = ff[i];
    else       flows[(10+(f-4))*per + r] = fb[(f-4)*per + r];
    return;
  }
  b -= MG_INIT;
  if (b < MG_FA){
    int ci = b / 24;
    int pix = (b - ci*24)*256 + tid;
    const int dsts[5] = {4,7,9,13,14};
    const float* A; const float* S;
    switch(ci){
      case 0: A = ff;          S = ff + 2*HW_; break;
      case 1: A = ff + 2*HW_;  S = ff + 4*HW_; break;
      case 2: A = ff + 4*HW_;  S = ff + 6*HW_; break;
      case 3: A = fb + 2*HW_;  S = fb;         break;
      default:A = fb + 4*HW_;  S = fb + 2*HW_; break;
    }
    float* D = flows + dsts[ci]*2*HW_;
    float ax = A[pix], ay = A[HW_+pix];
    float px = (float)(pix % W_) + ax;
    float py = (float)(pix / W_) + ay;
    D[pix]      = ax + bilin2(S,      px, py);
    D[HW_+pix]  = ay + bilin2(S+HW_,  px, py);
    return;
  }
  b -= MG_FA;
  {
    int idx = b*256 + tid;          // < 103680 exactly
    int pair = idx / 10368, r = idx - pair*10368;
    int pxi = r >> 5, q8 = r & 31;
    int t = pair >> 1, z = pair & 1;
    int y, x;
    if (pxi < 98){ y = 0;  x = pxi; }
    else if (pxi < 196){ y = 65; x = pxi-98; }
    else if (pxi < 260){ y = pxi-196+1; x = 0; }
    else { y = pxi-260+1; x = 97; }
    bf16* pad = z ? pad1 : pad0;
    uint4 zz; zz.x = zz.y = zz.z = zz.w = 0u;
    *(uint4*)(pad + (((size_t)t*PH_ + y)*PW_ + x)*C_ + q8*8) = zz;
  }
}

// ----------------------------------------------------------- implicit GEMM
// R0-verified loop: BM=128, BN=256, BK=64, 4 waves, wave tile 64x128,
// 48 KB LDS -> 2 blocks/CU. Riders bx>=240 run flowBC. NEW (R8): byy==2
// blocks own ALL 20 attn logits per unit (nc in [320,480)); epilogue does
// exact f32 softmax via two 40 KB LDS passes (reusing staging LDS) and
// writes w16 directly -> kills prep_k + the 39 MB v_aw roundtrip.
#define BM 128
#define BN 256
#define BK 64

// fused val (byy 0) + oa (byy 1..2) conv-GEMM + flowBC tail + softmax epi
__global__ __launch_bounds__(256,2) void gemm12_k(const bf16* __restrict__ Av,
                                                  const bf16* __restrict__ Aq,
                                                  const bf16* __restrict__ WTv,
                                                  const bf16* __restrict__ WToa,
                                                  const float* __restrict__ bv,
                                                  const float* __restrict__ boa,
                                                  bf16* __restrict__ outv,
                                                  float* __restrict__ P,
                                                  __half* __restrict__ w16,
                                                  const float* __restrict__ ff,
                                                  const float* __restrict__ fb,
                                                  float* __restrict__ flows){
  __shared__ __align__(16) char shm[49152];
  bf16* As = (bf16*)shm;               // 16 KB
  bf16* Bs = (bf16*)(shm + 16384);     // 32 KB
  float* smax = (float*)shm;           // epilogue reuse: 128x80 f32 = 40 KB
  int tid = threadIdx.x;
  int bx = blockIdx.x, byy = blockIdx.y;

  if (bx >= 240){
    // -------- flow compose stages B + C (72 rider blocks) --------
    int gy = byy;
    int pix = (bx-240)*256 + tid;
    float gx = (float)(pix % W_), gyy = (float)(pix / W_);
    if (gy == 0){
      const float* A   = flows + 4*2*HW_;
      const float* S23 = ff + 4*HW_;
      const float* S34 = ff + 6*HW_;
      float ax = A[pix], ay = A[HW_+pix];
      float px = gx + ax, py = gyy + ay;
      float c3x = ax + bilin2(S23,      px, py);
      float c3y = ay + bilin2(S23+HW_,  px, py);
      float* D3 = flows + 5*2*HW_;
      D3[pix] = c3x; D3[HW_+pix] = c3y;
      px = gx + c3x; py = gyy + c3y;
      float* D4 = flows + 6*2*HW_;
      D4[pix]     = c3x + bilin2(S34,     px, py);
      D4[HW_+pix] = c3y + bilin2(S34+HW_, px, py);
    } else if (gy == 1){
      const float* A = flows + 7*2*HW_;
      const float* S = ff + 6*HW_;
      float ax = A[pix], ay = A[HW_+pix];
      float px = gx + ax, py = gyy + ay;
      float* D = flows + 8*2*HW_;
      D[pix]     = ax + bilin2(S,     px, py);
      D[HW_+pix] = ay + bilin2(S+HW_, px, py);
    } else {
      const float* A = flows + 14*2*HW_;
      const float* S = fb;
      float ax = A[pix], ay = A[HW_+pix];
      float px = gx + ax, py = gyy + ay;
      float* D = flows + 15*2*HW_;
      D[pix]     = ax + bilin2(S,     px, py);
      D[HW_+pix] = ay + bilin2(S+HW_, px, py);
    }
    return;
  }

  int lane = tid & 63, wvi = tid >> 6;
  int wm = wvi & 1, wn = wvi >> 1;
  int quad = lane >> 4, l15 = lane & 15;
  bool isval = byy == 0;
  const bf16* Apad  = isval ? Av  : Aq;
  const bf16* WT    = isval ? WTv : WToa;
  const float* bias = isval ? bv  : boa;
  int nby = isval ? 0 : byy - 1;

  int srow = tid >> 3;
  int c8   = (tid & 7) ^ (srow & 7);
  long abase[4];
  #pragma unroll
  for (int j=0;j<4;++j){
    int p = j*32 + srow;
    int Pm = bx*BM + p;
    int t = Pm / HW_, rem = Pm - t*HW_;
    int y = rem / W_, x = rem - y*W_;
    abase[j] = ((long)(t*PH_ + y)*PW_ + x)*C_ + c8*8;
  }
  const bf16* bbase = WT + (size_t)(nby*BN + srow)*2304 + c8*8;

  float4v acc[4][8];
  #pragma unroll
  for (int jn=0;jn<8;++jn){
    float bvv = bias[nby*BN + wn*128 + jn*16 + l15];
    #pragma unroll
    for (int i=0;i<4;++i){ acc[i][jn][0]=bvv; acc[i][jn][1]=bvv; acc[i][jn][2]=bvv; acc[i][jn][3]=bvv; }
  }

  for (int kt=0; kt<36; ++kt){
    int tap = kt >> 2, kc = (kt & 3) << 6;
    int dy = tap/3, dx = tap - dy*3;
    long ash = (long)(dy*PW_ + dx)*C_ + kc;
    long bsh = (long)kt*64;
    __syncthreads();
    #pragma unroll
    for (int j=0;j<4;++j)
      gl2lds16(Apad + abase[j] + ash, As + (j*256+tid)*8);
    #pragma unroll
    for (int j=0;j<8;++j)
      gl2lds16(bbase + (size_t)j*32*2304 + bsh, Bs + (j*256+tid)*8);
    __syncthreads();
    #pragma unroll
    for (int kk=0; kk<2; ++kk){
      int slot = ((kk<<2) + quad) ^ (l15 & 7);
      short8 af[4], bfr[8];
      #pragma unroll
      for (int jn=0;jn<8;++jn)
        bfr[jn] = *(const short8*)(Bs + (wn*128 + jn*16 + l15)*BK + slot*8);
      #pragma unroll
      for (int i=0;i<4;++i)
        af[i] = *(const short8*)(As + (wm*64 + i*16 + l15)*BK + slot*8);
      #pragma unroll
      for (int i=0;i<4;++i)
        #pragma unroll
        for (int jn=0;jn<8;++jn)
          acc[i][jn] = __builtin_amdgcn_mfma_f32_16x16x32_bf16(af[i], bfr[jn], acc[i][jn], 0,0,0);
    }
  }

  // ---- standard epilogue: outv (val) / P (offset cols) ----
  #pragma unroll
  for (int i=0;i<4;++i){
    int mr = bx*BM + wm*64 + i*16 + quad*4;
    #pragma unroll
    for (int jn=0;jn<8;++jn){
      int nc = nby*BN + wn*128 + jn*16 + l15;
      #pragma unroll
      for (int r=0;r<4;++r){
        float v = acc[i][jn][r];
        long m = mr + r;
        if (isval){
          outv[m*256 + nc] = __float2bfloat16(v);
        } else if (nc < 320){
          int h = nc/40, rr = nc - h*40;
          int l = rr >> 3, pxy = rr & 7;
          P[((size_t)l*UNITS_ + m*8 + h)*8 + pxy] = v;
        }
      }
    }
  }

  // ---- softmax epilogue (byy==2 only): logits nc in [320,480) ----
  if (byy == 2){
    #pragma unroll
    for (int pass=0; pass<2; ++pass){
      int cbase = 320 + pass*80;
      __syncthreads();                  // LDS free (staging reads / prev pass done)
      #pragma unroll
      for (int i=0;i<4;++i){
        int row0 = wm*64 + i*16 + quad*4;
        #pragma unroll
        for (int jn=0;jn<8;++jn){
          int nc = 256 + wn*128 + jn*16 + l15;
          int c = nc - cbase;
          if ((unsigned)c < 80u){
            #pragma unroll
            for (int r=0;r<4;++r)
              smax[(row0+r)*80 + c] = acc[i][jn][r];
          }
        }
      }
      __syncthreads();
      // 512 units this pass (row 0..127 x hhh 0..3); 2 per thread
      #pragma unroll
      for (int k=0;k<2;++k){
        int lu = tid + k*256;
        int row = lu >> 2, hhh = lu & 3;
        const float* e = smax + row*80 + hhh*20;
        float mx = -1e30f;
        #pragma unroll
        for (int ii=0;ii<20;++ii) mx = fmaxf(mx, e[ii]);
        float s = 0.f;
        float ex[20];
        #pragma unroll
        for (int ii=0;ii<20;++ii){ ex[ii] = __expf(e[ii]-mx); s += ex[ii]; }
        float inv = 1.f/s;
        int unit = (bx*128 + row)*8 + pass*4 + hhh;
        __half2* o2 = (__half2*)(w16 + (size_t)unit*20);
        #pragma unroll
        for (int ii=0;ii<10;++ii)
          o2[ii] = __floats2half2_rn(ex[2*ii]*inv, ex[2*ii+1]*inv);
      }
    }
  }
}

// output conv: N=256 (one by), epilogue writes NCHW f32 directly
__global__ __launch_bounds__(256,2) void gemm_out_k(const bf16* __restrict__ Apad,
                                                    const bf16* __restrict__ WT,
                                                    const float* __restrict__ bias,
                                                    float* __restrict__ out){
  __shared__ __align__(16) bf16 As[BM*BK];
  __shared__ __align__(16) bf16 Bs[BN*BK];
  int tid = threadIdx.x;
  int lane = tid & 63, wvi = tid >> 6;
  int wm = wvi & 1, wn = wvi >> 1;
  int quad = lane >> 4, l15 = lane & 15;
  int bx = blockIdx.x;

  int srow = tid >> 3;
  int c8   = (tid & 7) ^ (srow & 7);
  long abase[4];
  #pragma unroll
  for (int j=0;j<4;++j){
    int p = j*32 + srow;
    int Pm = bx*BM + p;
    int t = Pm / HW_, rem = Pm - t*HW_;
    int y = rem / W_, x = rem - y*W_;
    abase[j] = ((long)(t*PH_ + y)*PW_ + x)*C_ + c8*8;
  }
  const bf16* bbase = WT + (size_t)srow*2304 + c8*8;

  float4v acc[4][8];
  #pragma unroll
  for (int jn=0;jn<8;++jn){
    float bvv = bias[wn*128 + jn*16 + l15];
    #pragma unroll
    for (int i=0;i<4;++i){ acc[i][jn][0]=bvv; acc[i][jn][1]=bvv; acc[i][jn][2]=bvv; acc[i][jn][3]=bvv; }
  }

  for (int kt=0; kt<36; ++kt){
    int tap = kt >> 2, kc = (kt & 3) << 6;
    int dy = tap/3, dx = tap - dy*3;
    long ash = (long)(dy*PW_ + dx)*C_ + kc;
    long bsh = (long)kt*64;
    __syncthreads();
    #pragma unroll
    for (int j=0;j<4;++j)
      gl2lds16(Apad + abase[j] + ash, As + (j*256+tid)*8);
    #pragma unroll
    for (int j=0;j<8;++j)
      gl2lds16(bbase + (size_t)j*32*2304 + bsh, Bs + (j*256+tid)*8);
    __syncthreads();
    #pragma unroll
    for (int kk=0; kk<2; ++kk){
      int slot = ((kk<<2) + quad) ^ (l15 & 7);
      short8 af[4], bfr[8];
      #pragma unroll
      for (int jn=0;jn<8;++jn)
        bfr[jn] = *(const short8*)(Bs + (wn*128 + jn*16 + l15)*BK + slot*8);
      #pragma unroll
      for (int i=0;i<4;++i)
        af[i] = *(const short8*)(As + (wm*64 + i*16 + l15)*BK + slot*8);
      #pragma unroll
      for (int i=0;i<4;++i)
        #pragma unroll
        for (int jn=0;jn<8;++jn)
          acc[i][jn] = __builtin_amdgcn_mfma_f32_16x16x32_bf16(af[i], bfr[jn], acc[i][jn], 0,0,0);
    }
  }

  int t = (bx*BM) / HW_;
  #pragma unroll
  for (int i=0;i<4;++i){
    int m = bx*BM + wm*64 + i*16 + quad*4;
    int pix = m - t*HW_;
    #pragma unroll
    for (int jn=0;jn<8;++jn){
      int nc = wn*128 + jn*16 + l15;
      *(float4v*)(out + ((size_t)(t*C_ + nc))*HW_ + pix) = acc[i][jn];
    }
  }
}

// ---------------------------------------------------------------- prep tab
__device__ const int g_slotTab[25] = {
  -1,  0,  4,  5,  6,
  10, -1,  1,  7,  8,
  13, 11, -1,  2,  9,
  15, 14, 12, -1,  3,
  15, 14, 12, -1,  3 };

// ------------------------------------------------------- per-level sampling
template<bool FIRST, bool LAST>
__global__ __launch_bounds__(256) void phase_k(const unsigned* __restrict__ vimg0,
                                               const float2*  __restrict__ Pl,
                                               const __half*  __restrict__ wl,
                                               const float*   __restrict__ ref,
                                               const float*   __restrict__ flows,
                                               int lvl,
                                               __half2* __restrict__ acc,
                                               bf16* __restrict__ attn_pad){
  __shared__ float4 sW[16][4];
  __shared__ int4   sI[16][4];
  int tid = threadIdx.x;
  if (tid < 64){
    int g = tid >> 2, p = tid & 3;
    int unit = blockIdx.x*16 + g;
    float2 pr = Pl[(size_t)unit*4 + p];
    float w = __half2float(wl[(size_t)unit*20 + p]);
    int q = unit >> 3;
    int t_q = q / HW_, pix = q - t_q*HW_;
    int slot = g_slotTab[t_q*5 + lvl];
    float ax = 0.f, ay = 0.f;
    if (slot >= 0){ ax = flows[slot*2*HW_ + pix]; ay = flows[slot*2*HW_ + HW_ + pix]; }
    float ppx = pr.x + ref[(q*5+lvl)*2+0]*(float)W_ - 0.5f + ax;
    float ppy = pr.y + ref[(q*5+lvl)*2+1]*(float)H_ - 0.5f + ay;
    float x0f = floorf(ppx), y0f = floorf(ppy);
    float fx = ppx - x0f,    fy = ppy - y0f;
    int x0 = (int)x0f, y0 = (int)y0f;
    int x1 = x0+1, y1 = y0+1;
    float wx0 = 1.f-fx, wx1 = fx, wy0 = 1.f-fy, wy1 = fy;
    if ((unsigned)x0 >= (unsigned)W_) wx0 = 0.f;
    if ((unsigned)x1 >= (unsigned)W_) wx1 = 0.f;
    if ((unsigned)y0 >= (unsigned)H_) wy0 = 0.f;
    if ((unsigned)y1 >= (unsigned)H_) wy1 = 0.f;
    int xc0 = min(max(x0,0),W_-1), xc1 = min(max(x1,0),W_-1);
    int yc0 = min(max(y0,0),H_-1), yc1 = min(max(y1,0),H_-1);
    sW[g][p] = make_float4(w*wx0*wy0, w*wx1*wy0, w*wx0*wy1, w*wx1*wy1);
    sI[g][p] = make_int4((yc0*W_+xc0)*128, (yc0*W_+xc1)*128,
                         (yc1*W_+xc0)*128, (yc1*W_+xc1)*128);
  }
  __syncthreads();
  int g = tid >> 4, e = tid & 15;
  int unit = blockIdx.x*16 + g;
  int q = unit >> 3, h = unit & 7;
  const unsigned* vimg = vimg0 + h*16 + e;
  float a0, a1;
  if (FIRST){ a0 = 0.f; a1 = 0.f; }
  else { __half2 c = acc[(size_t)unit*16 + e]; a0 = __low2float(c); a1 = __high2float(c); }
  #pragma unroll
  for (int p=0; p<4; ++p){
    float4 w4 = sW[g][p];
    int4   i4 = sI[g][p];
    unsigned u00 = vimg[i4.x], u10 = vimg[i4.y];
    unsigned u01 = vimg[i4.z], u11 = vimg[i4.w];
    union {unsigned v; float f;} lo, hi;
    lo.v = u00<<16; hi.v = u00 & 0xffff0000u;
    a0 = fmaf(w4.x, lo.f, a0); a1 = fmaf(w4.x, hi.f, a1);
    lo.v = u10<<16; hi.v = u10 & 0xffff0000u;
    a0 = fmaf(w4.y, lo.f, a0); a1 = fmaf(w4.y, hi.f, a1);
    lo.v = u01<<16; hi.v = u01 & 0xffff0000u;
    a0 = fmaf(w4.z, lo.f, a0); a1 = fmaf(w4.z, hi.f, a1);
    lo.v = u11<<16; hi.v = u11 & 0xffff0000u;
    a0 = fmaf(w4.w, lo.f, a0); a1 = fmaf(w4.w, hi.f, a1);
  }
  if (LAST){
    int t_q = q / HW_, pix = q - t_q*HW_;
    int yq = pix / W_, xq = pix - yq*W_;
    union {unsigned u; bf16 hh[2];} pk;
    pk.hh[0] = __float2bfloat16(a0);
    pk.hh[1] = __float2bfloat16(a1);
    *(unsigned*)(attn_pad + (((size_t)t_q*PH_ + yq+1)*PW_ + xq+1)*C_ + h*DH_ + e*2) = pk.u;
  } else {
    acc[(size_t)unit*16 + e] = __floats2half2_rn(a0, a1);
  }
}

// ---------------------------------------------------------------- launcher
extern "C" void kernel_launch(void* const* d_in, const int* in_sizes, int n_in,
                              void* d_out, int out_size, void* d_ws, size_t ws_size,
                              hipStream_t stream) {
  const float* query   = (const float*)d_in[0];
  const float* in_flat = (const float*)d_in[1];
  const float* refpts  = (const float*)d_in[2];
  const float* ff      = (const float*)d_in[6];
  const float* fb      = (const float*)d_in[7];
  const float* w_off   = (const float*)d_in[8];
  const float* b_off   = (const float*)d_in[9];
  const float* w_attn  = (const float*)d_in[10];
  const float* b_attn  = (const float*)d_in[11];
  const float* w_val   = (const float*)d_in[12];
  const float* b_val   = (const float*)d_in[13];
  const float* w_out   = (const float*)d_in[14];
  const float* b_out   = (const float*)d_in[15];
  float* out = (float*)d_out;

  // ---- memory map (peak 113,334,272 B) ----
  char* ws = (char*)d_ws;
  bf16*  v_pad   = (bf16*) (ws + 0);            // 16,558,080  in_flat pad -> attn_pad
  bf16*  q_pad   = (bf16*) (ws + 16558080);     // 16,558,080  (dead after gemm12)
  __half2* acc   = (__half2*)(ws + 16558080);   // 15,728,640  (late, over dead q_pad)
  bf16*  v_val   = (bf16*) (ws + 33116160);     // 15,728,640  gather source
  float* P       = (float*)(ws + 48844800);     // 39,321,600  [5][UNITS][4][2] f32 raw
  __half* w16    = (__half*)(ws + 88166400);    //  9,830,400  (written by gemm12 epi)
  float* v_flows = (float*)(ws + 107827200);    //    786,432
  bf16*  WT_val  = (bf16*) (ws + 108613632);    //  1,179,648
  bf16*  WT_oa   = (bf16*) (ws + 109793280);    //  2,359,296
  bf16*  WT_out  = (bf16*) (ws + 112152576);    //  1,179,648
  float* bias_oa = (float*)(ws + 113332224);    //      2,048  -> end 113,334,272
  bf16*  attn_pad = v_pad;
  if (ws_size < (size_t)113334272) return;

  // mega prologue: pad+cast, weight transpose, flow init, flow A, border zero
  mega0_k<<<MG_PAD+MG_WT+MG_INIT+MG_FA+MG_BZ, 256, 0, stream>>>(
      in_flat, query, v_pad, q_pad,
      w_val, w_off, w_attn, w_out, b_off, b_attn,
      WT_val, WT_oa, WT_out, bias_oa, ff, fb, v_flows);

  // fused val+oa conv-GEMM + flowBC riders + softmax epilogue (byy==2)
  gemm12_k<<<dim3(264, 3), 256, 0, stream>>>(v_pad, q_pad, WT_val, WT_oa,
                                             b_val, bias_oa, v_val, P, w16,
                                             ff, fb, v_flows);

  // per-level sampling phases (L2-resident gather slices, half2 carry)
  {
    const unsigned* vb = (const unsigned*)v_val;
    phase_k<true ,false><<<UNITS_/16, 256, 0, stream>>>(vb + 0ul*HW_*128,
        (const float2*)(P + 0ul*UNITS_*8), w16 + 0,  refpts, v_flows, 0, acc, attn_pad);
    phase_k<false,false><<<UNITS_/16, 256, 0, stream>>>(vb + 1ul*HW_*128,
        (const float2*)(P + 1ul*UNITS_*8), w16 + 4,  refpts, v_flows, 1, acc, attn_pad);
    phase_k<false,false><<<UNITS_/16, 256, 0, stream>>>(vb + 2ul*HW_*128,
        (const float2*)(P + 2ul*UNITS_*8), w16 + 8,  refpts, v_flows, 2, acc, attn_pad);
    phase_k<false,false><<<UNITS_/16, 256, 0, stream>>>(vb + 3ul*HW_*128,
        (const float2*)(P + 3ul*UNITS_*8), w16 + 12, refpts, v_flows, 3, acc, attn_pad);
    phase_k<false,true ><<<UNITS_/16, 256, 0, stream>>>(vb + 4ul*HW_*128,
        (const float2*)(P + 4ul*UNITS_*8), w16 + 16, refpts, v_flows, 4, acc, attn_pad);
  }

  // output conv, direct NCHW f32 epilogue
  gemm_out_k<<<dim3(240, 1), 256, 0, stream>>>(attn_pad, WT_out, b_out, out);
}

// Round 9
// 437.130 us; speedup vs baseline: 2.8479x; 1.0177x over previous
//
#include <hip/hip_runtime.h>
#include <hip/hip_bf16.h>
#include <hip/hip_fp16.h>

typedef __hip_bfloat16 bf16;
typedef __attribute__((ext_vector_type(8))) short short8;
typedef __attribute__((ext_vector_type(4))) float float4v;

#define T_  5
#define H_  64
#define W_  96
#define HW_ (H_*W_)
#define C_  256
#define NH_ 8
#define DH_ 32
#define NL_ 5
#define NP_ 4
#define LQ_ (T_*HW_)
#define UNITS_ (LQ_*NH_)          // 245760

// padded geometry: [T][66][98][256] bf16
#define PH_ 66
#define PW_ 98

static __device__ __forceinline__ void gl2lds16(const bf16* g, bf16* l){
  __builtin_amdgcn_global_load_lds(
      (const __attribute__((address_space(1))) unsigned int*)g,
      (__attribute__((address_space(3))) unsigned int*)l, 16, 0, 0);
}

// ------------------------------------------------------- bilinear (zero pad)
static __device__ __forceinline__ float bilin2(const float* __restrict__ img,
                                               float px, float py){
  float x0f = floorf(px), y0f = floorf(py);
  int x0 = (int)x0f, y0 = (int)y0f;
  float fx = px - x0f, fy = py - y0f;
  int x1 = x0+1, y1 = y0+1;
  bool vx0 = (x0>=0)&&(x0<W_), vx1 = (x1>=0)&&(x1<W_);
  bool vy0 = (y0>=0)&&(y0<H_), vy1 = (y1>=0)&&(y1<H_);
  float c00 = (vx0&&vy0)? img[y0*W_+x0] : 0.f;
  float c10 = (vx1&&vy0)? img[y0*W_+x1] : 0.f;
  float c01 = (vx0&&vy1)? img[y1*W_+x0] : 0.f;
  float c11 = (vx1&&vy1)? img[y1*W_+x1] : 0.f;
  return c00*(1.f-fx)*(1.f-fy) + c10*fx*(1.f-fy) + c01*(1.f-fx)*fy + c11*fx*fy;
}

// ------------------------------------------------------------- mega prologue
#define MG_PAD   960
#define MG_WT    1025
#define MG_INIT  336
#define MG_FA    120
#define MG_BZ    405
__global__ __launch_bounds__(256) void mega0_k(
    const float* __restrict__ in0, const float* __restrict__ in1,
    bf16* __restrict__ pad0, bf16* __restrict__ pad1,
    const float* __restrict__ wv, const float* __restrict__ wo,
    const float* __restrict__ wa, const float* __restrict__ wout,
    const float* __restrict__ bo, const float* __restrict__ ba,
    bf16* __restrict__ WTv, bf16* __restrict__ WToa, bf16* __restrict__ WTout,
    float* __restrict__ boa,
    const float* __restrict__ ff, const float* __restrict__ fb,
    float* __restrict__ flows)
{
  __shared__ __align__(16) char smem[33792];
  int b = blockIdx.x, tid = threadIdx.x;
  if (b < MG_PAD){
    bf16 (*sb)[66] = (bf16(*)[66])smem;
    int z = b / 480, r = b - z*480;
    int t = r / 96, bxp = r - t*96;
    const float* in = z ? in1 : in0;
    bf16* pad       = z ? pad1 : pad0;
    int pix0 = bxp*64;
    int pl = tid & 63, cg = tid >> 6;
    #pragma unroll 4
    for (int it=0; it<64; ++it){
      int c = it*4 + cg;
      sb[c][pl] = __float2bfloat16(in[((size_t)t*C_ + c)*HW_ + pix0 + pl]);
    }
    __syncthreads();
    for (int p=0; p<64; ++p){
      int pix = pix0 + p;
      int y = pix/W_, x = pix - y*W_;
      pad[(((size_t)t*PH_ + y+1)*PW_ + x+1)*C_ + tid] = sb[tid][p];
    }
    return;
  }
  b -= MG_PAD;
  if (b < MG_WT){
    if (b == 1024){
      #pragma unroll
      for (int k=0;k<2;++k){
        int n = tid + k*256;
        float v = 0.f;
        if (n < 320) v = bo[n]; else if (n < 480) v = ba[n-320];
        boa[n] = v;
      }
      return;
    }
    float* ld = (float*)smem;
    const float* src; bf16* dst;
    if (b < 256){ src = wv + (size_t)b*2304; dst = WTv + (size_t)b*2304; }
    else if (b < 768){
      int n = b-256; dst = WToa + (size_t)n*2304;
      src = (n<320) ? (wo + (size_t)n*2304)
          : ((n<480) ? (wa + (size_t)(n-320)*2304) : (const float*)0);
    } else { int n = b-768; src = wout + (size_t)n*2304; dst = WTout + (size_t)n*2304; }
    if (src){
      #pragma unroll
      for (int k=0;k<9;++k) ld[tid + k*256] = src[tid + k*256];
      __syncthreads();
      #pragma unroll
      for (int k=0;k<9;++k){
        int o = tid + k*256; int tap = o >> 8, ci = o & 255;
        dst[o] = __float2bfloat16(ld[ci*9 + tap]);
      }
    } else {
      #pragma unroll
      for (int k=0;k<9;++k) dst[tid + k*256] = __float2bfloat16(0.f);
    }
    return;
  }
  b -= MG_WT;
  if (b < MG_INIT){
    int i = b*256 + tid;            // < 86016
    const int per = 2*HW_;
    int f = i/per, r = i - f*per;
    if (f < 4) flows[f*per + r]          = ff[i];
    else       flows[(10+(f-4))*per + r] = fb[(f-4)*per + r];
    return;
  }
  b -= MG_INIT;
  if (b < MG_FA){
    int ci = b / 24;
    int pix = (b - ci*24)*256 + tid;
    const int dsts[5] = {4,7,9,13,14};
    const float* A; const float* S;
    switch(ci){
      case 0: A = ff;          S = ff + 2*HW_; break;
      case 1: A = ff + 2*HW_;  S = ff + 4*HW_; break;
      case 2: A = ff + 4*HW_;  S = ff + 6*HW_; break;
      case 3: A = fb + 2*HW_;  S = fb;         break;
      default:A = fb + 4*HW_;  S = fb + 2*HW_; break;
    }
    float* D = flows + dsts[ci]*2*HW_;
    float ax = A[pix], ay = A[HW_+pix];
    float px = (float)(pix % W_) + ax;
    float py = (float)(pix / W_) + ay;
    D[pix]      = ax + bilin2(S,      px, py);
    D[HW_+pix]  = ay + bilin2(S+HW_,  px, py);
    return;
  }
  b -= MG_FA;
  {
    int idx = b*256 + tid;          // < 103680 exactly
    int pair = idx / 10368, r = idx - pair*10368;
    int pxi = r >> 5, q8 = r & 31;
    int t = pair >> 1, z = pair & 1;
    int y, x;
    if (pxi < 98){ y = 0;  x = pxi; }
    else if (pxi < 196){ y = 65; x = pxi-98; }
    else if (pxi < 260){ y = pxi-196+1; x = 0; }
    else { y = pxi-260+1; x = 97; }
    bf16* pad = z ? pad1 : pad0;
    uint4 zz; zz.x = zz.y = zz.z = zz.w = 0u;
    *(uint4*)(pad + (((size_t)t*PH_ + y)*PW_ + x)*C_ + q8*8) = zz;
  }
}

// ----------------------------------------------------------- implicit GEMM
// R0-verified loop: BM=128, BN=256, BK=64, 4 waves, wave tile 64x128,
// 48 KB LDS -> 2 blocks/CU. Riders bx>=240 run flowBC. byy==2 epilogue does
// exact f32 softmax via two 40 KB LDS passes, writing w16 in LEVEL-MAJOR
// [5][UNITS][4] layout (R9: dense 2 MB read slice per phase).
#define BM 128
#define BN 256
#define BK 64

// fused val (byy 0) + oa (byy 1..2) conv-GEMM + flowBC tail + softmax epi
__global__ __launch_bounds__(256,2) void gemm12_k(const bf16* __restrict__ Av,
                                                  const bf16* __restrict__ Aq,
                                                  const bf16* __restrict__ WTv,
                                                  const bf16* __restrict__ WToa,
                                                  const float* __restrict__ bv,
                                                  const float* __restrict__ boa,
                                                  bf16* __restrict__ outv,
                                                  float* __restrict__ P,
                                                  __half* __restrict__ w16,
                                                  const float* __restrict__ ff,
                                                  const float* __restrict__ fb,
                                                  float* __restrict__ flows){
  __shared__ __align__(16) char shm[49152];
  bf16* As = (bf16*)shm;               // 16 KB
  bf16* Bs = (bf16*)(shm + 16384);     // 32 KB
  float* smax = (float*)shm;           // epilogue reuse: 128x80 f32 = 40 KB
  int tid = threadIdx.x;
  int bx = blockIdx.x, byy = blockIdx.y;

  if (bx >= 240){
    // -------- flow compose stages B + C (72 rider blocks) --------
    int gy = byy;
    int pix = (bx-240)*256 + tid;
    float gx = (float)(pix % W_), gyy = (float)(pix / W_);
    if (gy == 0){
      const float* A   = flows + 4*2*HW_;
      const float* S23 = ff + 4*HW_;
      const float* S34 = ff + 6*HW_;
      float ax = A[pix], ay = A[HW_+pix];
      float px = gx + ax, py = gyy + ay;
      float c3x = ax + bilin2(S23,      px, py);
      float c3y = ay + bilin2(S23+HW_,  px, py);
      float* D3 = flows + 5*2*HW_;
      D3[pix] = c3x; D3[HW_+pix] = c3y;
      px = gx + c3x; py = gyy + c3y;
      float* D4 = flows + 6*2*HW_;
      D4[pix]     = c3x + bilin2(S34,     px, py);
      D4[HW_+pix] = c3y + bilin2(S34+HW_, px, py);
    } else if (gy == 1){
      const float* A = flows + 7*2*HW_;
      const float* S = ff + 6*HW_;
      float ax = A[pix], ay = A[HW_+pix];
      float px = gx + ax, py = gyy + ay;
      float* D = flows + 8*2*HW_;
      D[pix]     = ax + bilin2(S,     px, py);
      D[HW_+pix] = ay + bilin2(S+HW_, px, py);
    } else {
      const float* A = flows + 14*2*HW_;
      const float* S = fb;
      float ax = A[pix], ay = A[HW_+pix];
      float px = gx + ax, py = gyy + ay;
      float* D = flows + 15*2*HW_;
      D[pix]     = ax + bilin2(S,     px, py);
      D[HW_+pix] = ay + bilin2(S+HW_, px, py);
    }
    return;
  }

  int lane = tid & 63, wvi = tid >> 6;
  int wm = wvi & 1, wn = wvi >> 1;
  int quad = lane >> 4, l15 = lane & 15;
  bool isval = byy == 0;
  const bf16* Apad  = isval ? Av  : Aq;
  const bf16* WT    = isval ? WTv : WToa;
  const float* bias = isval ? bv  : boa;
  int nby = isval ? 0 : byy - 1;

  int srow = tid >> 3;
  int c8   = (tid & 7) ^ (srow & 7);
  long abase[4];
  #pragma unroll
  for (int j=0;j<4;++j){
    int p = j*32 + srow;
    int Pm = bx*BM + p;
    int t = Pm / HW_, rem = Pm - t*HW_;
    int y = rem / W_, x = rem - y*W_;
    abase[j] = ((long)(t*PH_ + y)*PW_ + x)*C_ + c8*8;
  }
  const bf16* bbase = WT + (size_t)(nby*BN + srow)*2304 + c8*8;

  float4v acc[4][8];
  #pragma unroll
  for (int jn=0;jn<8;++jn){
    float bvv = bias[nby*BN + wn*128 + jn*16 + l15];
    #pragma unroll
    for (int i=0;i<4;++i){ acc[i][jn][0]=bvv; acc[i][jn][1]=bvv; acc[i][jn][2]=bvv; acc[i][jn][3]=bvv; }
  }

  for (int kt=0; kt<36; ++kt){
    int tap = kt >> 2, kc = (kt & 3) << 6;
    int dy = tap/3, dx = tap - dy*3;
    long ash = (long)(dy*PW_ + dx)*C_ + kc;
    long bsh = (long)kt*64;
    __syncthreads();
    #pragma unroll
    for (int j=0;j<4;++j)
      gl2lds16(Apad + abase[j] + ash, As + (j*256+tid)*8);
    #pragma unroll
    for (int j=0;j<8;++j)
      gl2lds16(bbase + (size_t)j*32*2304 + bsh, Bs + (j*256+tid)*8);
    __syncthreads();
    #pragma unroll
    for (int kk=0; kk<2; ++kk){
      int slot = ((kk<<2) + quad) ^ (l15 & 7);
      short8 af[4], bfr[8];
      #pragma unroll
      for (int jn=0;jn<8;++jn)
        bfr[jn] = *(const short8*)(Bs + (wn*128 + jn*16 + l15)*BK + slot*8);
      #pragma unroll
      for (int i=0;i<4;++i)
        af[i] = *(const short8*)(As + (wm*64 + i*16 + l15)*BK + slot*8);
      #pragma unroll
      for (int i=0;i<4;++i)
        #pragma unroll
        for (int jn=0;jn<8;++jn)
          acc[i][jn] = __builtin_amdgcn_mfma_f32_16x16x32_bf16(af[i], bfr[jn], acc[i][jn], 0,0,0);
    }
  }

  // ---- standard epilogue: outv (val) / P (offset cols) ----
  #pragma unroll
  for (int i=0;i<4;++i){
    int mr = bx*BM + wm*64 + i*16 + quad*4;
    #pragma unroll
    for (int jn=0;jn<8;++jn){
      int nc = nby*BN + wn*128 + jn*16 + l15;
      #pragma unroll
      for (int r=0;r<4;++r){
        float v = acc[i][jn][r];
        long m = mr + r;
        if (isval){
          outv[m*256 + nc] = __float2bfloat16(v);
        } else if (nc < 320){
          int h = nc/40, rr = nc - h*40;
          int l = rr >> 3, pxy = rr & 7;
          P[((size_t)l*UNITS_ + m*8 + h)*8 + pxy] = v;
        }
      }
    }
  }

  // ---- softmax epilogue (byy==2 only): logits nc in [320,480) ----
  if (byy == 2){
    #pragma unroll
    for (int pass=0; pass<2; ++pass){
      int cbase = 320 + pass*80;
      __syncthreads();                  // LDS free (staging reads / prev pass done)
      #pragma unroll
      for (int i=0;i<4;++i){
        int row0 = wm*64 + i*16 + quad*4;
        #pragma unroll
        for (int jn=0;jn<8;++jn){
          int nc = 256 + wn*128 + jn*16 + l15;
          int c = nc - cbase;
          if ((unsigned)c < 80u){
            #pragma unroll
            for (int r=0;r<4;++r)
              smax[(row0+r)*80 + c] = acc[i][jn][r];
          }
        }
      }
      __syncthreads();
      // 512 units this pass (row 0..127 x hhh 0..3); 2 per thread
      #pragma unroll
      for (int k=0;k<2;++k){
        int lu = tid + k*256;
        int row = lu >> 2, hhh = lu & 3;
        const float* e = smax + row*80 + hhh*20;
        float mx = -1e30f;
        #pragma unroll
        for (int ii=0;ii<20;++ii) mx = fmaxf(mx, e[ii]);
        float s = 0.f;
        float ex[20];
        #pragma unroll
        for (int ii=0;ii<20;++ii){ ex[ii] = __expf(e[ii]-mx); s += ex[ii]; }
        float inv = 1.f/s;
        int unit = (bx*128 + row)*8 + pass*4 + hhh;
        // level-major w16: [5][UNITS][4]
        #pragma unroll
        for (int l=0;l<5;++l){
          __half2* o2 = (__half2*)(w16 + (size_t)l*(UNITS_*4) + (size_t)unit*4);
          o2[0] = __floats2half2_rn(ex[l*4+0]*inv, ex[l*4+1]*inv);
          o2[1] = __floats2half2_rn(ex[l*4+2]*inv, ex[l*4+3]*inv);
        }
      }
    }
  }
}

// output conv: N=256 (one by), epilogue writes NCHW f32 directly
__global__ __launch_bounds__(256,2) void gemm_out_k(const bf16* __restrict__ Apad,
                                                    const bf16* __restrict__ WT,
                                                    const float* __restrict__ bias,
                                                    float* __restrict__ out){
  __shared__ __align__(16) bf16 As[BM*BK];
  __shared__ __align__(16) bf16 Bs[BN*BK];
  int tid = threadIdx.x;
  int lane = tid & 63, wvi = tid >> 6;
  int wm = wvi & 1, wn = wvi >> 1;
  int quad = lane >> 4, l15 = lane & 15;
  int bx = blockIdx.x;

  int srow = tid >> 3;
  int c8   = (tid & 7) ^ (srow & 7);
  long abase[4];
  #pragma unroll
  for (int j=0;j<4;++j){
    int p = j*32 + srow;
    int Pm = bx*BM + p;
    int t = Pm / HW_, rem = Pm - t*HW_;
    int y = rem / W_, x = rem - y*W_;
    abase[j] = ((long)(t*PH_ + y)*PW_ + x)*C_ + c8*8;
  }
  const bf16* bbase = WT + (size_t)srow*2304 + c8*8;

  float4v acc[4][8];
  #pragma unroll
  for (int jn=0;jn<8;++jn){
    float bvv = bias[wn*128 + jn*16 + l15];
    #pragma unroll
    for (int i=0;i<4;++i){ acc[i][jn][0]=bvv; acc[i][jn][1]=bvv; acc[i][jn][2]=bvv; acc[i][jn][3]=bvv; }
  }

  for (int kt=0; kt<36; ++kt){
    int tap = kt >> 2, kc = (kt & 3) << 6;
    int dy = tap/3, dx = tap - dy*3;
    long ash = (long)(dy*PW_ + dx)*C_ + kc;
    long bsh = (long)kt*64;
    __syncthreads();
    #pragma unroll
    for (int j=0;j<4;++j)
      gl2lds16(Apad + abase[j] + ash, As + (j*256+tid)*8);
    #pragma unroll
    for (int j=0;j<8;++j)
      gl2lds16(bbase + (size_t)j*32*2304 + bsh, Bs + (j*256+tid)*8);
    __syncthreads();
    #pragma unroll
    for (int kk=0; kk<2; ++kk){
      int slot = ((kk<<2) + quad) ^ (l15 & 7);
      short8 af[4], bfr[8];
      #pragma unroll
      for (int jn=0;jn<8;++jn)
        bfr[jn] = *(const short8*)(Bs + (wn*128 + jn*16 + l15)*BK + slot*8);
      #pragma unroll
      for (int i=0;i<4;++i)
        af[i] = *(const short8*)(As + (wm*64 + i*16 + l15)*BK + slot*8);
      #pragma unroll
      for (int i=0;i<4;++i)
        #pragma unroll
        for (int jn=0;jn<8;++jn)
          acc[i][jn] = __builtin_amdgcn_mfma_f32_16x16x32_bf16(af[i], bfr[jn], acc[i][jn], 0,0,0);
    }
  }

  int t = (bx*BM) / HW_;
  #pragma unroll
  for (int i=0;i<4;++i){
    int m = bx*BM + wm*64 + i*16 + quad*4;
    int pix = m - t*HW_;
    #pragma unroll
    for (int jn=0;jn<8;++jn){
      int nc = wn*128 + jn*16 + l15;
      *(float4v*)(out + ((size_t)(t*C_ + nc))*HW_ + pix) = acc[i][jn];
    }
  }
}

// ---------------------------------------------------------------- prep tab
__device__ const int g_slotTab[25] = {
  -1,  0,  4,  5,  6,
  10, -1,  1,  7,  8,
  13, 11, -1,  2,  9,
  15, 14, 12, -1,  3,
  15, 14, 12, -1,  3 };

// ------------------------------------------------------- per-level sampling
// R9: 32 units/block (grid 7680), w16 level-major dense read.
template<bool FIRST, bool LAST>
__global__ __launch_bounds__(256) void phase_k(const unsigned* __restrict__ vimg0,
                                               const float2*  __restrict__ Pl,
                                               const __half*  __restrict__ wl,
                                               const float*   __restrict__ ref,
                                               const float*   __restrict__ flows,
                                               int lvl,
                                               __half2* __restrict__ acc,
                                               bf16* __restrict__ attn_pad){
  __shared__ float4 sW[32][4];
  __shared__ int4   sI[32][4];
  int tid = threadIdx.x;
  if (tid < 128){
    int gg = tid >> 2, p = tid & 3;
    int unit = blockIdx.x*32 + gg;
    float2 pr = Pl[(size_t)unit*4 + p];
    float w = __half2float(wl[(size_t)unit*4 + p]);
    int q = unit >> 3;
    int t_q = q / HW_, pix = q - t_q*HW_;
    int slot = g_slotTab[t_q*5 + lvl];
    float ax = 0.f, ay = 0.f;
    if (slot >= 0){ ax = flows[slot*2*HW_ + pix]; ay = flows[slot*2*HW_ + HW_ + pix]; }
    float ppx = pr.x + ref[(q*5+lvl)*2+0]*(float)W_ - 0.5f + ax;
    float ppy = pr.y + ref[(q*5+lvl)*2+1]*(float)H_ - 0.5f + ay;
    float x0f = floorf(ppx), y0f = floorf(ppy);
    float fx = ppx - x0f,    fy = ppy - y0f;
    int x0 = (int)x0f, y0 = (int)y0f;
    int x1 = x0+1, y1 = y0+1;
    float wx0 = 1.f-fx, wx1 = fx, wy0 = 1.f-fy, wy1 = fy;
    if ((unsigned)x0 >= (unsigned)W_) wx0 = 0.f;
    if ((unsigned)x1 >= (unsigned)W_) wx1 = 0.f;
    if ((unsigned)y0 >= (unsigned)H_) wy0 = 0.f;
    if ((unsigned)y1 >= (unsigned)H_) wy1 = 0.f;
    int xc0 = min(max(x0,0),W_-1), xc1 = min(max(x1,0),W_-1);
    int yc0 = min(max(y0,0),H_-1), yc1 = min(max(y1,0),H_-1);
    sW[gg][p] = make_float4(w*wx0*wy0, w*wx1*wy0, w*wx0*wy1, w*wx1*wy1);
    sI[gg][p] = make_int4((yc0*W_+xc0)*128, (yc0*W_+xc1)*128,
                          (yc1*W_+xc0)*128, (yc1*W_+xc1)*128);
  }
  __syncthreads();
  int g = tid >> 4, e = tid & 15;
  int h = g & 7;                          // unit&7 == g&7 for both j halves
  const unsigned* vimg = vimg0 + h*16 + e;
  #pragma unroll
  for (int j=0;j<2;++j){
    int unit = blockIdx.x*32 + j*16 + g;
    float a0, a1;
    if (FIRST){ a0 = 0.f; a1 = 0.f; }
    else { __half2 c = acc[(size_t)unit*16 + e]; a0 = __low2float(c); a1 = __high2float(c); }
    #pragma unroll
    for (int p=0; p<4; ++p){
      float4 w4 = sW[j*16+g][p];
      int4   i4 = sI[j*16+g][p];
      unsigned u00 = vimg[i4.x], u10 = vimg[i4.y];
      unsigned u01 = vimg[i4.z], u11 = vimg[i4.w];
      union {unsigned v; float f;} lo, hi;
      lo.v = u00<<16; hi.v = u00 & 0xffff0000u;
      a0 = fmaf(w4.x, lo.f, a0); a1 = fmaf(w4.x, hi.f, a1);
      lo.v = u10<<16; hi.v = u10 & 0xffff0000u;
      a0 = fmaf(w4.y, lo.f, a0); a1 = fmaf(w4.y, hi.f, a1);
      lo.v = u01<<16; hi.v = u01 & 0xffff0000u;
      a0 = fmaf(w4.z, lo.f, a0); a1 = fmaf(w4.z, hi.f, a1);
      lo.v = u11<<16; hi.v = u11 & 0xffff0000u;
      a0 = fmaf(w4.w, lo.f, a0); a1 = fmaf(w4.w, hi.f, a1);
    }
    if (LAST){
      int q = unit >> 3;
      int t_q = q / HW_, pix = q - t_q*HW_;
      int yq = pix / W_, xq = pix - yq*W_;
      union {unsigned u; bf16 hh[2];} pk;
      pk.hh[0] = __float2bfloat16(a0);
      pk.hh[1] = __float2bfloat16(a1);
      *(unsigned*)(attn_pad + (((size_t)t_q*PH_ + yq+1)*PW_ + xq+1)*C_ + h*DH_ + e*2) = pk.u;
    } else {
      acc[(size_t)unit*16 + e] = __floats2half2_rn(a0, a1);
    }
  }
}

// ---------------------------------------------------------------- launcher
extern "C" void kernel_launch(void* const* d_in, const int* in_sizes, int n_in,
                              void* d_out, int out_size, void* d_ws, size_t ws_size,
                              hipStream_t stream) {
  const float* query   = (const float*)d_in[0];
  const float* in_flat = (const float*)d_in[1];
  const float* refpts  = (const float*)d_in[2];
  const float* ff      = (const float*)d_in[6];
  const float* fb      = (const float*)d_in[7];
  const float* w_off   = (const float*)d_in[8];
  const float* b_off   = (const float*)d_in[9];
  const float* w_attn  = (const float*)d_in[10];
  const float* b_attn  = (const float*)d_in[11];
  const float* w_val   = (const float*)d_in[12];
  const float* b_val   = (const float*)d_in[13];
  const float* w_out   = (const float*)d_in[14];
  const float* b_out   = (const float*)d_in[15];
  float* out = (float*)d_out;

  // ---- memory map (peak 113,334,272 B) ----
  char* ws = (char*)d_ws;
  bf16*  v_pad   = (bf16*) (ws + 0);            // 16,558,080  in_flat pad -> attn_pad
  bf16*  q_pad   = (bf16*) (ws + 16558080);     // 16,558,080  (dead after gemm12)
  __half2* acc   = (__half2*)(ws + 16558080);   // 15,728,640  (late, over dead q_pad)
  bf16*  v_val   = (bf16*) (ws + 33116160);     // 15,728,640  gather source
  float* P       = (float*)(ws + 48844800);     // 39,321,600  [5][UNITS][4][2] f32 raw
  __half* w16    = (__half*)(ws + 88166400);    //  9,830,400  [5][UNITS][4] (gemm12 epi)
  float* v_flows = (float*)(ws + 107827200);    //    786,432
  bf16*  WT_val  = (bf16*) (ws + 108613632);    //  1,179,648
  bf16*  WT_oa   = (bf16*) (ws + 109793280);    //  2,359,296
  bf16*  WT_out  = (bf16*) (ws + 112152576);    //  1,179,648
  float* bias_oa = (float*)(ws + 113332224);    //      2,048  -> end 113,334,272
  bf16*  attn_pad = v_pad;
  if (ws_size < (size_t)113334272) return;

  // mega prologue: pad+cast, weight transpose, flow init, flow A, border zero
  mega0_k<<<MG_PAD+MG_WT+MG_INIT+MG_FA+MG_BZ, 256, 0, stream>>>(
      in_flat, query, v_pad, q_pad,
      w_val, w_off, w_attn, w_out, b_off, b_attn,
      WT_val, WT_oa, WT_out, bias_oa, ff, fb, v_flows);

  // fused val+oa conv-GEMM + flowBC riders + softmax epilogue (byy==2)
  gemm12_k<<<dim3(264, 3), 256, 0, stream>>>(v_pad, q_pad, WT_val, WT_oa,
                                             b_val, bias_oa, v_val, P, w16,
                                             ff, fb, v_flows);

  // per-level sampling phases (L2-resident gather slices, half2 carry)
  {
    const unsigned* vb = (const unsigned*)v_val;
    phase_k<true ,false><<<UNITS_/32, 256, 0, stream>>>(vb + 0ul*HW_*128,
        (const float2*)(P + 0ul*UNITS_*8), w16 + 0ul*UNITS_*4, refpts, v_flows, 0, acc, attn_pad);
    phase_k<false,false><<<UNITS_/32, 256, 0, stream>>>(vb + 1ul*HW_*128,
        (const float2*)(P + 1ul*UNITS_*8), w16 + 1ul*UNITS_*4, refpts, v_flows, 1, acc, attn_pad);
    phase_k<false,false><<<UNITS_/32, 256, 0, stream>>>(vb + 2ul*HW_*128,
        (const float2*)(P + 2ul*UNITS_*8), w16 + 2ul*UNITS_*4, refpts, v_flows, 2, acc, attn_pad);
    phase_k<false,false><<<UNITS_/32, 256, 0, stream>>>(vb + 3ul*HW_*128,
        (const float2*)(P + 3ul*UNITS_*8), w16 + 3ul*UNITS_*4, refpts, v_flows, 3, acc, attn_pad);
    phase_k<false,true ><<<UNITS_/32, 256, 0, stream>>>(vb + 4ul*HW_*128,
        (const float2*)(P + 4ul*UNITS_*8), w16 + 4ul*UNITS_*4, refpts, v_flows, 4, acc, attn_pad);
  }

  // output conv, direct NCHW f32 epilogue
  gemm_out_k<<<dim3(240, 1), 256, 0, stream>>>(attn_pad, WT_out, b_out, out);
}

// Round 10
// 422.447 us; speedup vs baseline: 2.9469x; 1.0348x over previous
//
#include <hip/hip_runtime.h>
#include <hip/hip_bf16.h>
#include <hip/hip_fp16.h>

typedef __hip_bfloat16 bf16;
typedef __attribute__((ext_vector_type(8))) short short8;
typedef __attribute__((ext_vector_type(4))) float float4v;

#define T_  5
#define H_  64
#define W_  96
#define HW_ (H_*W_)
#define C_  256
#define NH_ 8
#define DH_ 32
#define NL_ 5
#define NP_ 4
#define LQ_ (T_*HW_)
#define UNITS_ (LQ_*NH_)          // 245760

// padded geometry: [T][66][98][256] bf16
#define PH_ 66
#define PW_ 98

static __device__ __forceinline__ void gl2lds16(const bf16* g, bf16* l){
  __builtin_amdgcn_global_load_lds(
      (const __attribute__((address_space(1))) unsigned int*)g,
      (__attribute__((address_space(3))) unsigned int*)l, 16, 0, 0);
}

// ------------------------------------------------------- bilinear (zero pad)
static __device__ __forceinline__ float bilin2(const float* __restrict__ img,
                                               float px, float py){
  float x0f = floorf(px), y0f = floorf(py);
  int x0 = (int)x0f, y0 = (int)y0f;
  float fx = px - x0f, fy = py - y0f;
  int x1 = x0+1, y1 = y0+1;
  bool vx0 = (x0>=0)&&(x0<W_), vx1 = (x1>=0)&&(x1<W_);
  bool vy0 = (y0>=0)&&(y0<H_), vy1 = (y1>=0)&&(y1<H_);
  float c00 = (vx0&&vy0)? img[y0*W_+x0] : 0.f;
  float c10 = (vx1&&vy0)? img[y0*W_+x1] : 0.f;
  float c01 = (vx0&&vy1)? img[y1*W_+x0] : 0.f;
  float c11 = (vx1&&vy1)? img[y1*W_+x1] : 0.f;
  return c00*(1.f-fx)*(1.f-fy) + c10*fx*(1.f-fy) + c01*(1.f-fx)*fy + c11*fx*fy;
}

// ------------------------------------------------------------- mega prologue
#define MG_PAD   960
#define MG_WT    1025
#define MG_INIT  336
#define MG_FA    120
#define MG_BZ    405
__global__ __launch_bounds__(256) void mega0_k(
    const float* __restrict__ in0, const float* __restrict__ in1,
    bf16* __restrict__ pad0, bf16* __restrict__ pad1,
    const float* __restrict__ wv, const float* __restrict__ wo,
    const float* __restrict__ wa, const float* __restrict__ wout,
    const float* __restrict__ bo, const float* __restrict__ ba,
    bf16* __restrict__ WTv, bf16* __restrict__ WToa, bf16* __restrict__ WTout,
    float* __restrict__ boa,
    const float* __restrict__ ff, const float* __restrict__ fb,
    float* __restrict__ flows)
{
  __shared__ __align__(16) char smem[33792];
  int b = blockIdx.x, tid = threadIdx.x;
  if (b < MG_PAD){
    bf16 (*sb)[66] = (bf16(*)[66])smem;
    int z = b / 480, r = b - z*480;
    int t = r / 96, bxp = r - t*96;
    const float* in = z ? in1 : in0;
    bf16* pad       = z ? pad1 : pad0;
    int pix0 = bxp*64;
    int pl = tid & 63, cg = tid >> 6;
    #pragma unroll 4
    for (int it=0; it<64; ++it){
      int c = it*4 + cg;
      sb[c][pl] = __float2bfloat16(in[((size_t)t*C_ + c)*HW_ + pix0 + pl]);
    }
    __syncthreads();
    for (int p=0; p<64; ++p){
      int pix = pix0 + p;
      int y = pix/W_, x = pix - y*W_;
      pad[(((size_t)t*PH_ + y+1)*PW_ + x+1)*C_ + tid] = sb[tid][p];
    }
    return;
  }
  b -= MG_PAD;
  if (b < MG_WT){
    if (b == 1024){
      #pragma unroll
      for (int k=0;k<2;++k){
        int n = tid + k*256;
        float v = 0.f;
        if (n < 320) v = bo[n]; else if (n < 480) v = ba[n-320];
        boa[n] = v;
      }
      return;
    }
    float* ld = (float*)smem;
    const float* src; bf16* dst;
    if (b < 256){ src = wv + (size_t)b*2304; dst = WTv + (size_t)b*2304; }
    else if (b < 768){
      int n = b-256; dst = WToa + (size_t)n*2304;
      src = (n<320) ? (wo + (size_t)n*2304)
          : ((n<480) ? (wa + (size_t)(n-320)*2304) : (const float*)0);
    } else { int n = b-768; src = wout + (size_t)n*2304; dst = WTout + (size_t)n*2304; }
    if (src){
      #pragma unroll
      for (int k=0;k<9;++k) ld[tid + k*256] = src[tid + k*256];
      __syncthreads();
      #pragma unroll
      for (int k=0;k<9;++k){
        int o = tid + k*256; int tap = o >> 8, ci = o & 255;
        dst[o] = __float2bfloat16(ld[ci*9 + tap]);
      }
    } else {
      #pragma unroll
      for (int k=0;k<9;++k) dst[tid + k*256] = __float2bfloat16(0.f);
    }
    return;
  }
  b -= MG_WT;
  if (b < MG_INIT){
    int i = b*256 + tid;            // < 86016
    const int per = 2*HW_;
    int f = i/per, r = i - f*per;
    if (f < 4) flows[f*per + r]          = ff[i];
    else       flows[(10+(f-4))*per + r] = fb[(f-4)*per + r];
    return;
  }
  b -= MG_INIT;
  if (b < MG_FA){
    int ci = b / 24;
    int pix = (b - ci*24)*256 + tid;
    const int dsts[5] = {4,7,9,13,14};
    const float* A; const float* S;
    switch(ci){
      case 0: A = ff;          S = ff + 2*HW_; break;
      case 1: A = ff + 2*HW_;  S = ff + 4*HW_; break;
      case 2: A = ff + 4*HW_;  S = ff + 6*HW_; break;
      case 3: A = fb + 2*HW_;  S = fb;         break;
      default:A = fb + 4*HW_;  S = fb + 2*HW_; break;
    }
    float* D = flows + dsts[ci]*2*HW_;
    float ax = A[pix], ay = A[HW_+pix];
    float px = (float)(pix % W_) + ax;
    float py = (float)(pix / W_) + ay;
    D[pix]      = ax + bilin2(S,      px, py);
    D[HW_+pix]  = ay + bilin2(S+HW_,  px, py);
    return;
  }
  b -= MG_FA;
  {
    int idx = b*256 + tid;          // < 103680 exactly
    int pair = idx / 10368, r = idx - pair*10368;
    int pxi = r >> 5, q8 = r & 31;
    int t = pair >> 1, z = pair & 1;
    int y, x;
    if (pxi < 98){ y = 0;  x = pxi; }
    else if (pxi < 196){ y = 65; x = pxi-98; }
    else if (pxi < 260){ y = pxi-196+1; x = 0; }
    else { y = pxi-260+1; x = 97; }
    bf16* pad = z ? pad1 : pad0;
    uint4 zz; zz.x = zz.y = zz.z = zz.w = 0u;
    *(uint4*)(pad + (((size_t)t*PH_ + y)*PW_ + x)*C_ + q8*8) = zz;
  }
}

// ----------------------------------------------------------- implicit GEMM
// R0-verified loop: BM=128, BN=256, BK=64, 4 waves, wave tile 64x128,
// 48 KB LDS -> 2+ blocks/CU. R10: 1-D grid with bijective XCD-chunked
// swizzle (T1/m204): lid=(orig%8)*90+orig/8, lid=bx*3+slab -> each XCD
// chunk holds 30 consecutive bx x {val,oa0,oa1} (A staged once per XCD,
// halo/WT L2-local). Riders orig>=720 run flowBC. byy==2-equivalent slab
// does the f32 softmax epilogue (w16 level-major).
#define BM 128
#define BN 256
#define BK 64

__global__ __launch_bounds__(256,2) void gemm12_k(const bf16* __restrict__ Av,
                                                  const bf16* __restrict__ Aq,
                                                  const bf16* __restrict__ WTv,
                                                  const bf16* __restrict__ WToa,
                                                  const float* __restrict__ bv,
                                                  const float* __restrict__ boa,
                                                  bf16* __restrict__ outv,
                                                  float* __restrict__ P,
                                                  __half* __restrict__ w16,
                                                  const float* __restrict__ ff,
                                                  const float* __restrict__ fb,
                                                  float* __restrict__ flows){
  __shared__ __align__(16) char shm[49152];
  bf16* As = (bf16*)shm;               // 16 KB
  bf16* Bs = (bf16*)(shm + 16384);     // 32 KB
  float* smax = (float*)shm;           // epilogue reuse: 128x80 f32 = 40 KB
  int tid = threadIdx.x;
  int orig = blockIdx.x;

  if (orig >= 720){
    // -------- flow compose stages B + C (72 rider blocks) --------
    int rid = orig - 720;
    int gy = rid / 24;
    int pix = (rid - gy*24)*256 + tid;
    float gx = (float)(pix % W_), gyy = (float)(pix / W_);
    if (gy == 0){
      const float* A   = flows + 4*2*HW_;
      const float* S23 = ff + 4*HW_;
      const float* S34 = ff + 6*HW_;
      float ax = A[pix], ay = A[HW_+pix];
      float px = gx + ax, py = gyy + ay;
      float c3x = ax + bilin2(S23,      px, py);
      float c3y = ay + bilin2(S23+HW_,  px, py);
      float* D3 = flows + 5*2*HW_;
      D3[pix] = c3x; D3[HW_+pix] = c3y;
      px = gx + c3x; py = gyy + c3y;
      float* D4 = flows + 6*2*HW_;
      D4[pix]     = c3x + bilin2(S34,     px, py);
      D4[HW_+pix] = c3y + bilin2(S34+HW_, px, py);
    } else if (gy == 1){
      const float* A = flows + 7*2*HW_;
      const float* S = ff + 6*HW_;
      float ax = A[pix], ay = A[HW_+pix];
      float px = gx + ax, py = gyy + ay;
      float* D = flows + 8*2*HW_;
      D[pix]     = ax + bilin2(S,     px, py);
      D[HW_+pix] = ay + bilin2(S+HW_, px, py);
    } else {
      const float* A = flows + 14*2*HW_;
      const float* S = fb;
      float ax = A[pix], ay = A[HW_+pix];
      float px = gx + ax, py = gyy + ay;
      float* D = flows + 15*2*HW_;
      D[pix]     = ax + bilin2(S,     px, py);
      D[HW_+pix] = ay + bilin2(S+HW_, px, py);
    }
    return;
  }

  // bijective XCD-chunked remap (720 = 8 x 90), slab-minor for A sharing
  int lid = (orig & 7)*90 + (orig >> 3);
  int bx = lid / 3;
  int s  = lid - bx*3;                 // 0 = val, 1/2 = oa halves

  int lane = tid & 63, wvi = tid >> 6;
  int wm = wvi & 1, wn = wvi >> 1;
  int quad = lane >> 4, l15 = lane & 15;
  bool isval = s == 0;
  const bf16* Apad  = isval ? Av  : Aq;
  const bf16* WT    = isval ? WTv : WToa;
  const float* bias = isval ? bv  : boa;
  int nby = isval ? 0 : s - 1;

  int srow = tid >> 3;
  int c8   = (tid & 7) ^ (srow & 7);
  long abase[4];
  #pragma unroll
  for (int j=0;j<4;++j){
    int p = j*32 + srow;
    int Pm = bx*BM + p;
    int t = Pm / HW_, rem = Pm - t*HW_;
    int y = rem / W_, x = rem - y*W_;
    abase[j] = ((long)(t*PH_ + y)*PW_ + x)*C_ + c8*8;
  }
  const bf16* bbase = WT + (size_t)(nby*BN + srow)*2304 + c8*8;

  float4v acc[4][8];
  #pragma unroll
  for (int jn=0;jn<8;++jn){
    float bvv = bias[nby*BN + wn*128 + jn*16 + l15];
    #pragma unroll
    for (int i=0;i<4;++i){ acc[i][jn][0]=bvv; acc[i][jn][1]=bvv; acc[i][jn][2]=bvv; acc[i][jn][3]=bvv; }
  }

  for (int kt=0; kt<36; ++kt){
    int tap = kt >> 2, kc = (kt & 3) << 6;
    int dy = tap/3, dx = tap - dy*3;
    long ash = (long)(dy*PW_ + dx)*C_ + kc;
    long bsh = (long)kt*64;
    __syncthreads();
    #pragma unroll
    for (int j=0;j<4;++j)
      gl2lds16(Apad + abase[j] + ash, As + (j*256+tid)*8);
    #pragma unroll
    for (int j=0;j<8;++j)
      gl2lds16(bbase + (size_t)j*32*2304 + bsh, Bs + (j*256+tid)*8);
    __syncthreads();
    #pragma unroll
    for (int kk=0; kk<2; ++kk){
      int slot = ((kk<<2) + quad) ^ (l15 & 7);
      short8 af[4], bfr[8];
      #pragma unroll
      for (int jn=0;jn<8;++jn)
        bfr[jn] = *(const short8*)(Bs + (wn*128 + jn*16 + l15)*BK + slot*8);
      #pragma unroll
      for (int i=0;i<4;++i)
        af[i] = *(const short8*)(As + (wm*64 + i*16 + l15)*BK + slot*8);
      #pragma unroll
      for (int i=0;i<4;++i)
        #pragma unroll
        for (int jn=0;jn<8;++jn)
          acc[i][jn] = __builtin_amdgcn_mfma_f32_16x16x32_bf16(af[i], bfr[jn], acc[i][jn], 0,0,0);
    }
  }

  // ---- standard epilogue: outv (val) / P (offset cols) ----
  #pragma unroll
  for (int i=0;i<4;++i){
    int mr = bx*BM + wm*64 + i*16 + quad*4;
    #pragma unroll
    for (int jn=0;jn<8;++jn){
      int nc = nby*BN + wn*128 + jn*16 + l15;
      #pragma unroll
      for (int r=0;r<4;++r){
        float v = acc[i][jn][r];
        long m = mr + r;
        if (isval){
          outv[m*256 + nc] = __float2bfloat16(v);
        } else if (nc < 320){
          int h = nc/40, rr = nc - h*40;
          int l = rr >> 3, pxy = rr & 7;
          P[((size_t)l*UNITS_ + m*8 + h)*8 + pxy] = v;
        }
      }
    }
  }

  // ---- softmax epilogue (s==2 only): logits nc in [320,480) ----
  if (s == 2){
    #pragma unroll
    for (int pass=0; pass<2; ++pass){
      int cbase = 320 + pass*80;
      __syncthreads();                  // LDS free (staging reads / prev pass done)
      #pragma unroll
      for (int i=0;i<4;++i){
        int row0 = wm*64 + i*16 + quad*4;
        #pragma unroll
        for (int jn=0;jn<8;++jn){
          int nc = 256 + wn*128 + jn*16 + l15;
          int c = nc - cbase;
          if ((unsigned)c < 80u){
            #pragma unroll
            for (int r=0;r<4;++r)
              smax[(row0+r)*80 + c] = acc[i][jn][r];
          }
        }
      }
      __syncthreads();
      // 512 units this pass (row 0..127 x hhh 0..3); 2 per thread
      #pragma unroll
      for (int k=0;k<2;++k){
        int lu = tid + k*256;
        int row = lu >> 2, hhh = lu & 3;
        const float* e = smax + row*80 + hhh*20;
        float mx = -1e30f;
        #pragma unroll
        for (int ii=0;ii<20;++ii) mx = fmaxf(mx, e[ii]);
        float ss = 0.f;
        float ex[20];
        #pragma unroll
        for (int ii=0;ii<20;++ii){ ex[ii] = __expf(e[ii]-mx); ss += ex[ii]; }
        float inv = 1.f/ss;
        int unit = (bx*128 + row)*8 + pass*4 + hhh;
        // level-major w16: [5][UNITS][4]
        #pragma unroll
        for (int l=0;l<5;++l){
          __half2* o2 = (__half2*)(w16 + (size_t)l*(UNITS_*4) + (size_t)unit*4);
          o2[0] = __floats2half2_rn(ex[l*4+0]*inv, ex[l*4+1]*inv);
          o2[1] = __floats2half2_rn(ex[l*4+2]*inv, ex[l*4+3]*inv);
        }
      }
    }
  }
}

// output conv: N=256, NCHW f32 epilogue; XCD-chunked bx remap (240 = 8x30)
__global__ __launch_bounds__(256,2) void gemm_out_k(const bf16* __restrict__ Apad,
                                                    const bf16* __restrict__ WT,
                                                    const float* __restrict__ bias,
                                                    float* __restrict__ out){
  __shared__ __align__(16) bf16 As[BM*BK];
  __shared__ __align__(16) bf16 Bs[BN*BK];
  int tid = threadIdx.x;
  int lane = tid & 63, wvi = tid >> 6;
  int wm = wvi & 1, wn = wvi >> 1;
  int quad = lane >> 4, l15 = lane & 15;
  int orig = blockIdx.x;
  int bx = (orig & 7)*30 + (orig >> 3);

  int srow = tid >> 3;
  int c8   = (tid & 7) ^ (srow & 7);
  long abase[4];
  #pragma unroll
  for (int j=0;j<4;++j){
    int p = j*32 + srow;
    int Pm = bx*BM + p;
    int t = Pm / HW_, rem = Pm - t*HW_;
    int y = rem / W_, x = rem - y*W_;
    abase[j] = ((long)(t*PH_ + y)*PW_ + x)*C_ + c8*8;
  }
  const bf16* bbase = WT + (size_t)srow*2304 + c8*8;

  float4v acc[4][8];
  #pragma unroll
  for (int jn=0;jn<8;++jn){
    float bvv = bias[wn*128 + jn*16 + l15];
    #pragma unroll
    for (int i=0;i<4;++i){ acc[i][jn][0]=bvv; acc[i][jn][1]=bvv; acc[i][jn][2]=bvv; acc[i][jn][3]=bvv; }
  }

  for (int kt=0; kt<36; ++kt){
    int tap = kt >> 2, kc = (kt & 3) << 6;
    int dy = tap/3, dx = tap - dy*3;
    long ash = (long)(dy*PW_ + dx)*C_ + kc;
    long bsh = (long)kt*64;
    __syncthreads();
    #pragma unroll
    for (int j=0;j<4;++j)
      gl2lds16(Apad + abase[j] + ash, As + (j*256+tid)*8);
    #pragma unroll
    for (int j=0;j<8;++j)
      gl2lds16(bbase + (size_t)j*32*2304 + bsh, Bs + (j*256+tid)*8);
    __syncthreads();
    #pragma unroll
    for (int kk=0; kk<2; ++kk){
      int slot = ((kk<<2) + quad) ^ (l15 & 7);
      short8 af[4], bfr[8];
      #pragma unroll
      for (int jn=0;jn<8;++jn)
        bfr[jn] = *(const short8*)(Bs + (wn*128 + jn*16 + l15)*BK + slot*8);
      #pragma unroll
      for (int i=0;i<4;++i)
        af[i] = *(const short8*)(As + (wm*64 + i*16 + l15)*BK + slot*8);
      #pragma unroll
      for (int i=0;i<4;++i)
        #pragma unroll
        for (int jn=0;jn<8;++jn)
          acc[i][jn] = __builtin_amdgcn_mfma_f32_16x16x32_bf16(af[i], bfr[jn], acc[i][jn], 0,0,0);
    }
  }

  int t = (bx*BM) / HW_;
  #pragma unroll
  for (int i=0;i<4;++i){
    int m = bx*BM + wm*64 + i*16 + quad*4;
    int pix = m - t*HW_;
    #pragma unroll
    for (int jn=0;jn<8;++jn){
      int nc = wn*128 + jn*16 + l15;
      *(float4v*)(out + ((size_t)(t*C_ + nc))*HW_ + pix) = acc[i][jn];
    }
  }
}

// ---------------------------------------------------------------- prep tab
__device__ const int g_slotTab[25] = {
  -1,  0,  4,  5,  6,
  10, -1,  1,  7,  8,
  13, 11, -1,  2,  9,
  15, 14, 12, -1,  3,
  15, 14, 12, -1,  3 };

// ------------------------------------------------------- per-level sampling
// 32 units/block (grid 7680), w16 level-major dense read.
template<bool FIRST, bool LAST>
__global__ __launch_bounds__(256) void phase_k(const unsigned* __restrict__ vimg0,
                                               const float2*  __restrict__ Pl,
                                               const __half*  __restrict__ wl,
                                               const float*   __restrict__ ref,
                                               const float*   __restrict__ flows,
                                               int lvl,
                                               __half2* __restrict__ acc,
                                               bf16* __restrict__ attn_pad){
  __shared__ float4 sW[32][4];
  __shared__ int4   sI[32][4];
  int tid = threadIdx.x;
  if (tid < 128){
    int gg = tid >> 2, p = tid & 3;
    int unit = blockIdx.x*32 + gg;
    float2 pr = Pl[(size_t)unit*4 + p];
    float w = __half2float(wl[(size_t)unit*4 + p]);
    int q = unit >> 3;
    int t_q = q / HW_, pix = q - t_q*HW_;
    int slot = g_slotTab[t_q*5 + lvl];
    float ax = 0.f, ay = 0.f;
    if (slot >= 0){ ax = flows[slot*2*HW_ + pix]; ay = flows[slot*2*HW_ + HW_ + pix]; }
    float ppx = pr.x + ref[(q*5+lvl)*2+0]*(float)W_ - 0.5f + ax;
    float ppy = pr.y + ref[(q*5+lvl)*2+1]*(float)H_ - 0.5f + ay;
    float x0f = floorf(ppx), y0f = floorf(ppy);
    float fx = ppx - x0f,    fy = ppy - y0f;
    int x0 = (int)x0f, y0 = (int)y0f;
    int x1 = x0+1, y1 = y0+1;
    float wx0 = 1.f-fx, wx1 = fx, wy0 = 1.f-fy, wy1 = fy;
    if ((unsigned)x0 >= (unsigned)W_) wx0 = 0.f;
    if ((unsigned)x1 >= (unsigned)W_) wx1 = 0.f;
    if ((unsigned)y0 >= (unsigned)H_) wy0 = 0.f;
    if ((unsigned)y1 >= (unsigned)H_) wy1 = 0.f;
    int xc0 = min(max(x0,0),W_-1), xc1 = min(max(x1,0),W_-1);
    int yc0 = min(max(y0,0),H_-1), yc1 = min(max(y1,0),H_-1);
    sW[gg][p] = make_float4(w*wx0*wy0, w*wx1*wy0, w*wx0*wy1, w*wx1*wy1);
    sI[gg][p] = make_int4((yc0*W_+xc0)*128, (yc0*W_+xc1)*128,
                          (yc1*W_+xc0)*128, (yc1*W_+xc1)*128);
  }
  __syncthreads();
  int g = tid >> 4, e = tid & 15;
  int h = g & 7;                          // unit&7 == g&7 for both j halves
  const unsigned* vimg = vimg0 + h*16 + e;
  #pragma unroll
  for (int j=0;j<2;++j){
    int unit = blockIdx.x*32 + j*16 + g;
    float a0, a1;
    if (FIRST){ a0 = 0.f; a1 = 0.f; }
    else { __half2 c = acc[(size_t)unit*16 + e]; a0 = __low2float(c); a1 = __high2float(c); }
    #pragma unroll
    for (int p=0; p<4; ++p){
      float4 w4 = sW[j*16+g][p];
      int4   i4 = sI[j*16+g][p];
      unsigned u00 = vimg[i4.x], u10 = vimg[i4.y];
      unsigned u01 = vimg[i4.z], u11 = vimg[i4.w];
      union {unsigned v; float f;} lo, hi;
      lo.v = u00<<16; hi.v = u00 & 0xffff0000u;
      a0 = fmaf(w4.x, lo.f, a0); a1 = fmaf(w4.x, hi.f, a1);
      lo.v = u10<<16; hi.v = u10 & 0xffff0000u;
      a0 = fmaf(w4.y, lo.f, a0); a1 = fmaf(w4.y, hi.f, a1);
      lo.v = u01<<16; hi.v = u01 & 0xffff0000u;
      a0 = fmaf(w4.z, lo.f, a0); a1 = fmaf(w4.z, hi.f, a1);
      lo.v = u11<<16; hi.v = u11 & 0xffff0000u;
      a0 = fmaf(w4.w, lo.f, a0); a1 = fmaf(w4.w, hi.f, a1);
    }
    if (LAST){
      int q = unit >> 3;
      int t_q = q / HW_, pix = q - t_q*HW_;
      int yq = pix / W_, xq = pix - yq*W_;
      union {unsigned u; bf16 hh[2];} pk;
      pk.hh[0] = __float2bfloat16(a0);
      pk.hh[1] = __float2bfloat16(a1);
      *(unsigned*)(attn_pad + (((size_t)t_q*PH_ + yq+1)*PW_ + xq+1)*C_ + h*DH_ + e*2) = pk.u;
    } else {
      acc[(size_t)unit*16 + e] = __floats2half2_rn(a0, a1);
    }
  }
}

// ---------------------------------------------------------------- launcher
extern "C" void kernel_launch(void* const* d_in, const int* in_sizes, int n_in,
                              void* d_out, int out_size, void* d_ws, size_t ws_size,
                              hipStream_t stream) {
  const float* query   = (const float*)d_in[0];
  const float* in_flat = (const float*)d_in[1];
  const float* refpts  = (const float*)d_in[2];
  const float* ff      = (const float*)d_in[6];
  const float* fb      = (const float*)d_in[7];
  const float* w_off   = (const float*)d_in[8];
  const float* b_off   = (const float*)d_in[9];
  const float* w_attn  = (const float*)d_in[10];
  const float* b_attn  = (const float*)d_in[11];
  const float* w_val   = (const float*)d_in[12];
  const float* b_val   = (const float*)d_in[13];
  const float* w_out   = (const float*)d_in[14];
  const float* b_out   = (const float*)d_in[15];
  float* out = (float*)d_out;

  // ---- memory map (peak 113,334,272 B) ----
  char* ws = (char*)d_ws;
  bf16*  v_pad   = (bf16*) (ws + 0);            // 16,558,080  in_flat pad -> attn_pad
  bf16*  q_pad   = (bf16*) (ws + 16558080);     // 16,558,080  (dead after gemm12)
  __half2* acc   = (__half2*)(ws + 16558080);   // 15,728,640  (late, over dead q_pad)
  bf16*  v_val   = (bf16*) (ws + 33116160);     // 15,728,640  gather source
  float* P       = (float*)(ws + 48844800);     // 39,321,600  [5][UNITS][4][2] f32 raw
  __half* w16    = (__half*)(ws + 88166400);    //  9,830,400  [5][UNITS][4] (gemm12 epi)
  float* v_flows = (float*)(ws + 107827200);    //    786,432
  bf16*  WT_val  = (bf16*) (ws + 108613632);    //  1,179,648
  bf16*  WT_oa   = (bf16*) (ws + 109793280);    //  2,359,296
  bf16*  WT_out  = (bf16*) (ws + 112152576);    //  1,179,648
  float* bias_oa = (float*)(ws + 113332224);    //      2,048  -> end 113,334,272
  bf16*  attn_pad = v_pad;
  if (ws_size < (size_t)113334272) return;

  // mega prologue: pad+cast, weight transpose, flow init, flow A, border zero
  mega0_k<<<MG_PAD+MG_WT+MG_INIT+MG_FA+MG_BZ, 256, 0, stream>>>(
      in_flat, query, v_pad, q_pad,
      w_val, w_off, w_attn, w_out, b_off, b_attn,
      WT_val, WT_oa, WT_out, bias_oa, ff, fb, v_flows);

  // fused val+oa conv-GEMM (1-D XCD-swizzled) + flowBC riders + softmax epi
  gemm12_k<<<792, 256, 0, stream>>>(v_pad, q_pad, WT_val, WT_oa,
                                    b_val, bias_oa, v_val, P, w16,
                                    ff, fb, v_flows);

  // per-level sampling phases (L2-resident gather slices, half2 carry)
  {
    const unsigned* vb = (const unsigned*)v_val;
    phase_k<true ,false><<<UNITS_/32, 256, 0, stream>>>(vb + 0ul*HW_*128,
        (const float2*)(P + 0ul*UNITS_*8), w16 + 0ul*UNITS_*4, refpts, v_flows, 0, acc, attn_pad);
    phase_k<false,false><<<UNITS_/32, 256, 0, stream>>>(vb + 1ul*HW_*128,
        (const float2*)(P + 1ul*UNITS_*8), w16 + 1ul*UNITS_*4, refpts, v_flows, 1, acc, attn_pad);
    phase_k<false,false><<<UNITS_/32, 256, 0, stream>>>(vb + 2ul*HW_*128,
        (const float2*)(P + 2ul*UNITS_*8), w16 + 2ul*UNITS_*4, refpts, v_flows, 2, acc, attn_pad);
    phase_k<false,false><<<UNITS_/32, 256, 0, stream>>>(vb + 3ul*HW_*128,
        (const float2*)(P + 3ul*UNITS_*8), w16 + 3ul*UNITS_*4, refpts, v_flows, 3, acc, attn_pad);
    phase_k<false,true ><<<UNITS_/32, 256, 0, stream>>>(vb + 4ul*HW_*128,
        (const float2*)(P + 4ul*UNITS_*8), w16 + 4ul*UNITS_*4, refpts, v_flows, 4, acc, attn_pad);
  }

  // output conv, direct NCHW f32 epilogue (XCD-swizzled bx)
  gemm_out_k<<<240, 256, 0, stream>>>(attn_pad, WT_out, b_out, out);
}

// Round 11
// 419.368 us; speedup vs baseline: 2.9685x; 1.0073x over previous
//
#include <hip/hip_runtime.h>
#include <hip/hip_bf16.h>
#include <hip/hip_fp16.h>

typedef __hip_bfloat16 bf16;
typedef __attribute__((ext_vector_type(8))) short short8;
typedef __attribute__((ext_vector_type(4))) float float4v;

#define T_  5
#define H_  64
#define W_  96
#define HW_ (H_*W_)
#define C_  256
#define NH_ 8
#define DH_ 32
#define NL_ 5
#define NP_ 4
#define LQ_ (T_*HW_)
#define UNITS_ (LQ_*NH_)          // 245760

// padded geometry: [T][66][98][256] bf16
#define PH_ 66
#define PW_ 98

static __device__ __forceinline__ void gl2lds16(const bf16* g, bf16* l){
  __builtin_amdgcn_global_load_lds(
      (const __attribute__((address_space(1))) unsigned int*)g,
      (__attribute__((address_space(3))) unsigned int*)l, 16, 0, 0);
}

// ------------------------------------------------------- bilinear (zero pad)
static __device__ __forceinline__ float bilin2(const float* __restrict__ img,
                                               float px, float py){
  float x0f = floorf(px), y0f = floorf(py);
  int x0 = (int)x0f, y0 = (int)y0f;
  float fx = px - x0f, fy = py - y0f;
  int x1 = x0+1, y1 = y0+1;
  bool vx0 = (x0>=0)&&(x0<W_), vx1 = (x1>=0)&&(x1<W_);
  bool vy0 = (y0>=0)&&(y0<H_), vy1 = (y1>=0)&&(y1<H_);
  float c00 = (vx0&&vy0)? img[y0*W_+x0] : 0.f;
  float c10 = (vx1&&vy0)? img[y0*W_+x1] : 0.f;
  float c01 = (vx0&&vy1)? img[y1*W_+x0] : 0.f;
  float c11 = (vx1&&vy1)? img[y1*W_+x1] : 0.f;
  return c00*(1.f-fx)*(1.f-fy) + c10*fx*(1.f-fy) + c01*(1.f-fx)*fy + c11*fx*fy;
}

// ------------------------------------------------------------- mega prologue
#define MG_PAD   960
#define MG_WT    1025
#define MG_INIT  336
#define MG_FA    120
#define MG_BZ    405
__global__ __launch_bounds__(256) void mega0_k(
    const float* __restrict__ in0, const float* __restrict__ in1,
    bf16* __restrict__ pad0, bf16* __restrict__ pad1,
    const float* __restrict__ wv, const float* __restrict__ wo,
    const float* __restrict__ wa, const float* __restrict__ wout,
    const float* __restrict__ bo, const float* __restrict__ ba,
    bf16* __restrict__ WTv, bf16* __restrict__ WToa, bf16* __restrict__ WTout,
    float* __restrict__ boa,
    const float* __restrict__ ff, const float* __restrict__ fb,
    float* __restrict__ flows)
{
  __shared__ __align__(16) char smem[33792];
  int b = blockIdx.x, tid = threadIdx.x;
  if (b < MG_PAD){
    bf16 (*sb)[66] = (bf16(*)[66])smem;
    int z = b / 480, r = b - z*480;
    int t = r / 96, bxp = r - t*96;
    const float* in = z ? in1 : in0;
    bf16* pad       = z ? pad1 : pad0;
    int pix0 = bxp*64;
    int pl = tid & 63, cg = tid >> 6;
    #pragma unroll 4
    for (int it=0; it<64; ++it){
      int c = it*4 + cg;
      sb[c][pl] = __float2bfloat16(in[((size_t)t*C_ + c)*HW_ + pix0 + pl]);
    }
    __syncthreads();
    for (int p=0; p<64; ++p){
      int pix = pix0 + p;
      int y = pix/W_, x = pix - y*W_;
      pad[(((size_t)t*PH_ + y+1)*PW_ + x+1)*C_ + tid] = sb[tid][p];
    }
    return;
  }
  b -= MG_PAD;
  if (b < MG_WT){
    if (b == 1024){
      #pragma unroll
      for (int k=0;k<2;++k){
        int n = tid + k*256;
        float v = 0.f;
        if (n < 320) v = bo[n]; else if (n < 480) v = ba[n-320];
        boa[n] = v;
      }
      return;
    }
    float* ld = (float*)smem;
    const float* src; bf16* dst;
    if (b < 256){ src = wv + (size_t)b*2304; dst = WTv + (size_t)b*2304; }
    else if (b < 768){
      int n = b-256; dst = WToa + (size_t)n*2304;
      src = (n<320) ? (wo + (size_t)n*2304)
          : ((n<480) ? (wa + (size_t)(n-320)*2304) : (const float*)0);
    } else { int n = b-768; src = wout + (size_t)n*2304; dst = WTout + (size_t)n*2304; }
    if (src){
      #pragma unroll
      for (int k=0;k<9;++k) ld[tid + k*256] = src[tid + k*256];
      __syncthreads();
      #pragma unroll
      for (int k=0;k<9;++k){
        int o = tid + k*256; int tap = o >> 8, ci = o & 255;
        dst[o] = __float2bfloat16(ld[ci*9 + tap]);
      }
    } else {
      #pragma unroll
      for (int k=0;k<9;++k) dst[tid + k*256] = __float2bfloat16(0.f);
    }
    return;
  }
  b -= MG_WT;
  if (b < MG_INIT){
    int i = b*256 + tid;            // < 86016
    const int per = 2*HW_;
    int f = i/per, r = i - f*per;
    if (f < 4) flows[f*per + r]          = ff[i];
    else       flows[(10+(f-4))*per + r] = fb[(f-4)*per + r];
    return;
  }
  b -= MG_INIT;
  if (b < MG_FA){
    int ci = b / 24;
    int pix = (b - ci*24)*256 + tid;
    const int dsts[5] = {4,7,9,13,14};
    const float* A; const float* S;
    switch(ci){
      case 0: A = ff;          S = ff + 2*HW_; break;
      case 1: A = ff + 2*HW_;  S = ff + 4*HW_; break;
      case 2: A = ff + 4*HW_;  S = ff + 6*HW_; break;
      case 3: A = fb + 2*HW_;  S = fb;         break;
      default:A = fb + 4*HW_;  S = fb + 2*HW_; break;
    }
    float* D = flows + dsts[ci]*2*HW_;
    float ax = A[pix], ay = A[HW_+pix];
    float px = (float)(pix % W_) + ax;
    float py = (float)(pix / W_) + ay;
    D[pix]      = ax + bilin2(S,      px, py);
    D[HW_+pix]  = ay + bilin2(S+HW_,  px, py);
    return;
  }
  b -= MG_FA;
  {
    int idx = b*256 + tid;          // < 103680 exactly
    int pair = idx / 10368, r = idx - pair*10368;
    int pxi = r >> 5, q8 = r & 31;
    int t = pair >> 1, z = pair & 1;
    int y, x;
    if (pxi < 98){ y = 0;  x = pxi; }
    else if (pxi < 196){ y = 65; x = pxi-98; }
    else if (pxi < 260){ y = pxi-196+1; x = 0; }
    else { y = pxi-260+1; x = 97; }
    bf16* pad = z ? pad1 : pad0;
    uint4 zz; zz.x = zz.y = zz.z = zz.w = 0u;
    *(uint4*)(pad + (((size_t)t*PH_ + y)*PW_ + x)*C_ + q8*8) = zz;
  }
}

// ----------------------------------------------------------- implicit GEMM
// R0-verified loop + R10 XCD-chunked swizzle: lid=(orig%8)*90+orig/8,
// lid=bx*3+slab -> XCD x owns bx in [30x,30x+30) -> units [30720x, +30720).
// Riders orig>=720 run flowBC. s==2 slab does f32 softmax epilogue
// (w16 level-major). R11: smax row stride 81 (odd) kills bank conflicts.
#define BM 128
#define BN 256
#define BK 64

__global__ __launch_bounds__(256,2) void gemm12_k(const bf16* __restrict__ Av,
                                                  const bf16* __restrict__ Aq,
                                                  const bf16* __restrict__ WTv,
                                                  const bf16* __restrict__ WToa,
                                                  const float* __restrict__ bv,
                                                  const float* __restrict__ boa,
                                                  bf16* __restrict__ outv,
                                                  float* __restrict__ P,
                                                  __half* __restrict__ w16,
                                                  const float* __restrict__ ff,
                                                  const float* __restrict__ fb,
                                                  float* __restrict__ flows){
  __shared__ __align__(16) char shm[49152];
  bf16* As = (bf16*)shm;               // 16 KB
  bf16* Bs = (bf16*)(shm + 16384);     // 32 KB
  float* smax = (float*)shm;           // epilogue reuse: 128x81 f32 = 41.5 KB
  int tid = threadIdx.x;
  int orig = blockIdx.x;

  if (orig >= 720){
    // -------- flow compose stages B + C (72 rider blocks) --------
    int rid = orig - 720;
    int gy = rid / 24;
    int pix = (rid - gy*24)*256 + tid;
    float gx = (float)(pix % W_), gyy = (float)(pix / W_);
    if (gy == 0){
      const float* A   = flows + 4*2*HW_;
      const float* S23 = ff + 4*HW_;
      const float* S34 = ff + 6*HW_;
      float ax = A[pix], ay = A[HW_+pix];
      float px = gx + ax, py = gyy + ay;
      float c3x = ax + bilin2(S23,      px, py);
      float c3y = ay + bilin2(S23+HW_,  px, py);
      float* D3 = flows + 5*2*HW_;
      D3[pix] = c3x; D3[HW_+pix] = c3y;
      px = gx + c3x; py = gyy + c3y;
      float* D4 = flows + 6*2*HW_;
      D4[pix]     = c3x + bilin2(S34,     px, py);
      D4[HW_+pix] = c3y + bilin2(S34+HW_, px, py);
    } else if (gy == 1){
      const float* A = flows + 7*2*HW_;
      const float* S = ff + 6*HW_;
      float ax = A[pix], ay = A[HW_+pix];
      float px = gx + ax, py = gyy + ay;
      float* D = flows + 8*2*HW_;
      D[pix]     = ax + bilin2(S,     px, py);
      D[HW_+pix] = ay + bilin2(S+HW_, px, py);
    } else {
      const float* A = flows + 14*2*HW_;
      const float* S = fb;
      float ax = A[pix], ay = A[HW_+pix];
      float px = gx + ax, py = gyy + ay;
      float* D = flows + 15*2*HW_;
      D[pix]     = ax + bilin2(S,     px, py);
      D[HW_+pix] = ay + bilin2(S+HW_, px, py);
    }
    return;
  }

  // bijective XCD-chunked remap (720 = 8 x 90), slab-minor for A sharing
  int lid = (orig & 7)*90 + (orig >> 3);
  int bx = lid / 3;
  int s  = lid - bx*3;                 // 0 = val, 1/2 = oa halves

  int lane = tid & 63, wvi = tid >> 6;
  int wm = wvi & 1, wn = wvi >> 1;
  int quad = lane >> 4, l15 = lane & 15;
  bool isval = s == 0;
  const bf16* Apad  = isval ? Av  : Aq;
  const bf16* WT    = isval ? WTv : WToa;
  const float* bias = isval ? bv  : boa;
  int nby = isval ? 0 : s - 1;

  int srow = tid >> 3;
  int c8   = (tid & 7) ^ (srow & 7);
  long abase[4];
  #pragma unroll
  for (int j=0;j<4;++j){
    int p = j*32 + srow;
    int Pm = bx*BM + p;
    int t = Pm / HW_, rem = Pm - t*HW_;
    int y = rem / W_, x = rem - y*W_;
    abase[j] = ((long)(t*PH_ + y)*PW_ + x)*C_ + c8*8;
  }
  const bf16* bbase = WT + (size_t)(nby*BN + srow)*2304 + c8*8;

  float4v acc[4][8];
  #pragma unroll
  for (int jn=0;jn<8;++jn){
    float bvv = bias[nby*BN + wn*128 + jn*16 + l15];
    #pragma unroll
    for (int i=0;i<4;++i){ acc[i][jn][0]=bvv; acc[i][jn][1]=bvv; acc[i][jn][2]=bvv; acc[i][jn][3]=bvv; }
  }

  for (int kt=0; kt<36; ++kt){
    int tap = kt >> 2, kc = (kt & 3) << 6;
    int dy = tap/3, dx = tap - dy*3;
    long ash = (long)(dy*PW_ + dx)*C_ + kc;
    long bsh = (long)kt*64;
    __syncthreads();
    #pragma unroll
    for (int j=0;j<4;++j)
      gl2lds16(Apad + abase[j] + ash, As + (j*256+tid)*8);
    #pragma unroll
    for (int j=0;j<8;++j)
      gl2lds16(bbase + (size_t)j*32*2304 + bsh, Bs + (j*256+tid)*8);
    __syncthreads();
    #pragma unroll
    for (int kk=0; kk<2; ++kk){
      int slot = ((kk<<2) + quad) ^ (l15 & 7);
      short8 af[4], bfr[8];
      #pragma unroll
      for (int jn=0;jn<8;++jn)
        bfr[jn] = *(const short8*)(Bs + (wn*128 + jn*16 + l15)*BK + slot*8);
      #pragma unroll
      for (int i=0;i<4;++i)
        af[i] = *(const short8*)(As + (wm*64 + i*16 + l15)*BK + slot*8);
      #pragma unroll
      for (int i=0;i<4;++i)
        #pragma unroll
        for (int jn=0;jn<8;++jn)
          acc[i][jn] = __builtin_amdgcn_mfma_f32_16x16x32_bf16(af[i], bfr[jn], acc[i][jn], 0,0,0);
    }
  }

  // ---- standard epilogue: outv (val) / P (offset cols) ----
  #pragma unroll
  for (int i=0;i<4;++i){
    int mr = bx*BM + wm*64 + i*16 + quad*4;
    #pragma unroll
    for (int jn=0;jn<8;++jn){
      int nc = nby*BN + wn*128 + jn*16 + l15;
      #pragma unroll
      for (int r=0;r<4;++r){
        float v = acc[i][jn][r];
        long m = mr + r;
        if (isval){
          outv[m*256 + nc] = __float2bfloat16(v);
        } else if (nc < 320){
          int h = nc/40, rr = nc - h*40;
          int l = rr >> 3, pxy = rr & 7;
          P[((size_t)l*UNITS_ + m*8 + h)*8 + pxy] = v;
        }
      }
    }
  }

  // ---- softmax epilogue (s==2 only): logits nc in [320,480) ----
  if (s == 2){
    #pragma unroll
    for (int pass=0; pass<2; ++pass){
      int cbase = 320 + pass*80;
      __syncthreads();                  // LDS free (staging reads / prev pass done)
      #pragma unroll
      for (int i=0;i<4;++i){
        int row0 = wm*64 + i*16 + quad*4;
        #pragma unroll
        for (int jn=0;jn<8;++jn){
          int nc = 256 + wn*128 + jn*16 + l15;
          int c = nc - cbase;
          if ((unsigned)c < 80u){
            #pragma unroll
            for (int r=0;r<4;++r)
              smax[(row0+r)*81 + c] = acc[i][jn][r];
          }
        }
      }
      __syncthreads();
      // 512 units this pass (row 0..127 x hhh 0..3); 2 per thread
      #pragma unroll
      for (int k=0;k<2;++k){
        int lu = tid + k*256;
        int row = lu >> 2, hhh = lu & 3;
        const float* e = smax + row*81 + hhh*20;
        float mx = -1e30f;
        #pragma unroll
        for (int ii=0;ii<20;++ii) mx = fmaxf(mx, e[ii]);
        float ss = 0.f;
        float ex[20];
        #pragma unroll
        for (int ii=0;ii<20;++ii){ ex[ii] = __expf(e[ii]-mx); ss += ex[ii]; }
        float inv = 1.f/ss;
        int unit = (bx*128 + row)*8 + pass*4 + hhh;
        // level-major w16: [5][UNITS][4]
        #pragma unroll
        for (int l=0;l<5;++l){
          __half2* o2 = (__half2*)(w16 + (size_t)l*(UNITS_*4) + (size_t)unit*4);
          o2[0] = __floats2half2_rn(ex[l*4+0]*inv, ex[l*4+1]*inv);
          o2[1] = __floats2half2_rn(ex[l*4+2]*inv, ex[l*4+3]*inv);
        }
      }
    }
  }
}

// output conv: N=256, NCHW f32 epilogue; XCD-chunked bx remap (240 = 8x30)
__global__ __launch_bounds__(256,2) void gemm_out_k(const bf16* __restrict__ Apad,
                                                    const bf16* __restrict__ WT,
                                                    const float* __restrict__ bias,
                                                    float* __restrict__ out){
  __shared__ __align__(16) bf16 As[BM*BK];
  __shared__ __align__(16) bf16 Bs[BN*BK];
  int tid = threadIdx.x;
  int lane = tid & 63, wvi = tid >> 6;
  int wm = wvi & 1, wn = wvi >> 1;
  int quad = lane >> 4, l15 = lane & 15;
  int orig = blockIdx.x;
  int bx = (orig & 7)*30 + (orig >> 3);

  int srow = tid >> 3;
  int c8   = (tid & 7) ^ (srow & 7);
  long abase[4];
  #pragma unroll
  for (int j=0;j<4;++j){
    int p = j*32 + srow;
    int Pm = bx*BM + p;
    int t = Pm / HW_, rem = Pm - t*HW_;
    int y = rem / W_, x = rem - y*W_;
    abase[j] = ((long)(t*PH_ + y)*PW_ + x)*C_ + c8*8;
  }
  const bf16* bbase = WT + (size_t)srow*2304 + c8*8;

  float4v acc[4][8];
  #pragma unroll
  for (int jn=0;jn<8;++jn){
    float bvv = bias[wn*128 + jn*16 + l15];
    #pragma unroll
    for (int i=0;i<4;++i){ acc[i][jn][0]=bvv; acc[i][jn][1]=bvv; acc[i][jn][2]=bvv; acc[i][jn][3]=bvv; }
  }

  for (int kt=0; kt<36; ++kt){
    int tap = kt >> 2, kc = (kt & 3) << 6;
    int dy = tap/3, dx = tap - dy*3;
    long ash = (long)(dy*PW_ + dx)*C_ + kc;
    long bsh = (long)kt*64;
    __syncthreads();
    #pragma unroll
    for (int j=0;j<4;++j)
      gl2lds16(Apad + abase[j] + ash, As + (j*256+tid)*8);
    #pragma unroll
    for (int j=0;j<8;++j)
      gl2lds16(bbase + (size_t)j*32*2304 + bsh, Bs + (j*256+tid)*8);
    __syncthreads();
    #pragma unroll
    for (int kk=0; kk<2; ++kk){
      int slot = ((kk<<2) + quad) ^ (l15 & 7);
      short8 af[4], bfr[8];
      #pragma unroll
      for (int jn=0;jn<8;++jn)
        bfr[jn] = *(const short8*)(Bs + (wn*128 + jn*16 + l15)*BK + slot*8);
      #pragma unroll
      for (int i=0;i<4;++i)
        af[i] = *(const short8*)(As + (wm*64 + i*16 + l15)*BK + slot*8);
      #pragma unroll
      for (int i=0;i<4;++i)
        #pragma unroll
        for (int jn=0;jn<8;++jn)
          acc[i][jn] = __builtin_amdgcn_mfma_f32_16x16x32_bf16(af[i], bfr[jn], acc[i][jn], 0,0,0);
    }
  }

  int t = (bx*BM) / HW_;
  #pragma unroll
  for (int i=0;i<4;++i){
    int m = bx*BM + wm*64 + i*16 + quad*4;
    int pix = m - t*HW_;
    #pragma unroll
    for (int jn=0;jn<8;++jn){
      int nc = wn*128 + jn*16 + l15;
      *(float4v*)(out + ((size_t)(t*C_ + nc))*HW_ + pix) = acc[i][jn];
    }
  }
}

// ---------------------------------------------------------------- prep tab
__device__ const int g_slotTab[25] = {
  -1,  0,  4,  5,  6,
  10, -1,  1,  7,  8,
  13, 11, -1,  2,  9,
  15, 14, 12, -1,  3,
  15, 14, 12, -1,  3 };

// ------------------------------------------------------- per-level sampling
// 32 units/block; R11: unit base XCD-aligned to gemm12's writer chunking
// (XCD x owns units [30720x, +30720)) -> P/w16/acc/attn_pad L2-local.
template<bool FIRST, bool LAST>
__global__ __launch_bounds__(256) void phase_k(const unsigned* __restrict__ vimg0,
                                               const float2*  __restrict__ Pl,
                                               const __half*  __restrict__ wl,
                                               const float*   __restrict__ ref,
                                               const float*   __restrict__ flows,
                                               int lvl,
                                               __half2* __restrict__ acc,
                                               bf16* __restrict__ attn_pad){
  __shared__ float4 sW[32][4];
  __shared__ int4   sI[32][4];
  int tid = threadIdx.x;
  int u0 = (blockIdx.x & 7)*30720 + (blockIdx.x >> 3)*32;   // XCD-aligned
  if (tid < 128){
    int gg = tid >> 2, p = tid & 3;
    int unit = u0 + gg;
    float2 pr = Pl[(size_t)unit*4 + p];
    float w = __half2float(wl[(size_t)unit*4 + p]);
    int q = unit >> 3;
    int t_q = q / HW_, pix = q - t_q*HW_;
    int slot = g_slotTab[t_q*5 + lvl];
    float ax = 0.f, ay = 0.f;
    if (slot >= 0){ ax = flows[slot*2*HW_ + pix]; ay = flows[slot*2*HW_ + HW_ + pix]; }
    float ppx = pr.x + ref[(q*5+lvl)*2+0]*(float)W_ - 0.5f + ax;
    float ppy = pr.y + ref[(q*5+lvl)*2+1]*(float)H_ - 0.5f + ay;
    float x0f = floorf(ppx), y0f = floorf(ppy);
    float fx = ppx - x0f,    fy = ppy - y0f;
    int x0 = (int)x0f, y0 = (int)y0f;
    int x1 = x0+1, y1 = y0+1;
    float wx0 = 1.f-fx, wx1 = fx, wy0 = 1.f-fy, wy1 = fy;
    if ((unsigned)x0 >= (unsigned)W_) wx0 = 0.f;
    if ((unsigned)x1 >= (unsigned)W_) wx1 = 0.f;
    if ((unsigned)y0 >= (unsigned)H_) wy0 = 0.f;
    if ((unsigned)y1 >= (unsigned)H_) wy1 = 0.f;
    int xc0 = min(max(x0,0),W_-1), xc1 = min(max(x1,0),W_-1);
    int yc0 = min(max(y0,0),H_-1), yc1 = min(max(y1,0),H_-1);
    sW[gg][p] = make_float4(w*wx0*wy0, w*wx1*wy0, w*wx0*wy1, w*wx1*wy1);
    sI[gg][p] = make_int4((yc0*W_+xc0)*128, (yc0*W_+xc1)*128,
                          (yc1*W_+xc0)*128, (yc1*W_+xc1)*128);
  }
  __syncthreads();
  int g = tid >> 4, e = tid & 15;
  int h = g & 7;                          // unit&7 == g&7 (u0 mult of 32)
  const unsigned* vimg = vimg0 + h*16 + e;
  #pragma unroll
  for (int j=0;j<2;++j){
    int unit = u0 + j*16 + g;
    float a0, a1;
    if (FIRST){ a0 = 0.f; a1 = 0.f; }
    else { __half2 c = acc[(size_t)unit*16 + e]; a0 = __low2float(c); a1 = __high2float(c); }
    #pragma unroll
    for (int p=0; p<4; ++p){
      float4 w4 = sW[j*16+g][p];
      int4   i4 = sI[j*16+g][p];
      unsigned u00 = vimg[i4.x], u10 = vimg[i4.y];
      unsigned u01 = vimg[i4.z], u11 = vimg[i4.w];
      union {unsigned v; float f;} lo, hi;
      lo.v = u00<<16; hi.v = u00 & 0xffff0000u;
      a0 = fmaf(w4.x, lo.f, a0); a1 = fmaf(w4.x, hi.f, a1);
      lo.v = u10<<16; hi.v = u10 & 0xffff0000u;
      a0 = fmaf(w4.y, lo.f, a0); a1 = fmaf(w4.y, hi.f, a1);
      lo.v = u01<<16; hi.v = u01 & 0xffff0000u;
      a0 = fmaf(w4.z, lo.f, a0); a1 = fmaf(w4.z, hi.f, a1);
      lo.v = u11<<16; hi.v = u11 & 0xffff0000u;
      a0 = fmaf(w4.w, lo.f, a0); a1 = fmaf(w4.w, hi.f, a1);
    }
    if (LAST){
      int q = unit >> 3;
      int t_q = q / HW_, pix = q - t_q*HW_;
      int yq = pix / W_, xq = pix - yq*W_;
      union {unsigned u; bf16 hh[2];} pk;
      pk.hh[0] = __float2bfloat16(a0);
      pk.hh[1] = __float2bfloat16(a1);
      *(unsigned*)(attn_pad + (((size_t)t_q*PH_ + yq+1)*PW_ + xq+1)*C_ + h*DH_ + e*2) = pk.u;
    } else {
      acc[(size_t)unit*16 + e] = __floats2half2_rn(a0, a1);
    }
  }
}

// ---------------------------------------------------------------- launcher
extern "C" void kernel_launch(void* const* d_in, const int* in_sizes, int n_in,
                              void* d_out, int out_size, void* d_ws, size_t ws_size,
                              hipStream_t stream) {
  const float* query   = (const float*)d_in[0];
  const float* in_flat = (const float*)d_in[1];
  const float* refpts  = (const float*)d_in[2];
  const float* ff      = (const float*)d_in[6];
  const float* fb      = (const float*)d_in[7];
  const float* w_off   = (const float*)d_in[8];
  const float* b_off   = (const float*)d_in[9];
  const float* w_attn  = (const float*)d_in[10];
  const float* b_attn  = (const float*)d_in[11];
  const float* w_val   = (const float*)d_in[12];
  const float* b_val   = (const float*)d_in[13];
  const float* w_out   = (const float*)d_in[14];
  const float* b_out   = (const float*)d_in[15];
  float* out = (float*)d_out;

  // ---- memory map (peak 113,334,272 B) ----
  char* ws = (char*)d_ws;
  bf16*  v_pad   = (bf16*) (ws + 0);            // 16,558,080  in_flat pad -> attn_pad
  bf16*  q_pad   = (bf16*) (ws + 16558080);     // 16,558,080  (dead after gemm12)
  __half2* acc   = (__half2*)(ws + 16558080);   // 15,728,640  (late, over dead q_pad)
  bf16*  v_val   = (bf16*) (ws + 33116160);     // 15,728,640  gather source
  float* P       = (float*)(ws + 48844800);     // 39,321,600  [5][UNITS][4][2] f32 raw
  __half* w16    = (__half*)(ws + 88166400);    //  9,830,400  [5][UNITS][4] (gemm12 epi)
  float* v_flows = (float*)(ws + 107827200);    //    786,432
  bf16*  WT_val  = (bf16*) (ws + 108613632);    //  1,179,648
  bf16*  WT_oa   = (bf16*) (ws + 109793280);    //  2,359,296
  bf16*  WT_out  = (bf16*) (ws + 112152576);    //  1,179,648
  float* bias_oa = (float*)(ws + 113332224);    //      2,048  -> end 113,334,272
  bf16*  attn_pad = v_pad;
  if (ws_size < (size_t)113334272) return;

  // mega prologue: pad+cast, weight transpose, flow init, flow A, border zero
  mega0_k<<<MG_PAD+MG_WT+MG_INIT+MG_FA+MG_BZ, 256, 0, stream>>>(
      in_flat, query, v_pad, q_pad,
      w_val, w_off, w_attn, w_out, b_off, b_attn,
      WT_val, WT_oa, WT_out, bias_oa, ff, fb, v_flows);

  // fused val+oa conv-GEMM (1-D XCD-swizzled) + flowBC riders + softmax epi
  gemm12_k<<<792, 256, 0, stream>>>(v_pad, q_pad, WT_val, WT_oa,
                                    b_val, bias_oa, v_val, P, w16,
                                    ff, fb, v_flows);

  // per-level sampling phases (L2-resident gather slices, half2 carry,
  // unit ranges XCD-aligned to gemm12's writer chunks)
  {
    const unsigned* vb = (const unsigned*)v_val;
    phase_k<true ,false><<<UNITS_/32, 256, 0, stream>>>(vb + 0ul*HW_*128,
        (const float2*)(P + 0ul*UNITS_*8), w16 + 0ul*UNITS_*4, refpts, v_flows, 0, acc, attn_pad);
    phase_k<false,false><<<UNITS_/32, 256, 0, stream>>>(vb + 1ul*HW_*128,
        (const float2*)(P + 1ul*UNITS_*8), w16 + 1ul*UNITS_*4, refpts, v_flows, 1, acc, attn_pad);
    phase_k<false,false><<<UNITS_/32, 256, 0, stream>>>(vb + 2ul*HW_*128,
        (const float2*)(P + 2ul*UNITS_*8), w16 + 2ul*UNITS_*4, refpts, v_flows, 2, acc, attn_pad);
    phase_k<false,false><<<UNITS_/32, 256, 0, stream>>>(vb + 3ul*HW_*128,
        (const float2*)(P + 3ul*UNITS_*8), w16 + 3ul*UNITS_*4, refpts, v_flows, 3, acc, attn_pad);
    phase_k<false,true ><<<UNITS_/32, 256, 0, stream>>>(vb + 4ul*HW_*128,
        (const float2*)(P + 4ul*UNITS_*8), w16 + 4ul*UNITS_*4, refpts, v_flows, 4, acc, attn_pad);
  }

  // output conv, direct NCHW f32 epilogue (XCD-swizzled bx)
  gemm_out_k<<<240, 256, 0, stream>>>(attn_pad, WT_out, b_out, out);
}